// Round 11
// baseline (862.859 us; speedup 1.0000x reference)
//
#include <hip/hip_runtime.h>
#include <hip/hip_bf16.h>

typedef __hip_bfloat16 bf16;

#define NN 50000      // nodes
#define NE 1600000    // edges (= 6250*256 exactly)
#define NG 128        // graphs
#define NB 128        // rna batch
#define SG 3000       // global seq (channels)
#define SL 2998       // local seq
#define VG 5          // global vocab
#define VL 65         // local vocab
#define EDB 6250      // edge blocks (NE/256)
#define AGB 12500     // agg blocks (NN/4)
#define MID 25000     // src bin boundary

__device__ __forceinline__ float b2f(bf16 x){ return __bfloat162float(x); }
__device__ __forceinline__ float blo(unsigned u){ return __uint_as_float(u << 16); }
__device__ __forceinline__ float bhi(unsigned u){ return __uint_as_float(u & 0xffff0000u); }

// ---------------- F1: edge_deg (src-binned)  U  buildA(g)  U  buildA(l) ----
__device__ void dev_buildA(const bf16* __restrict__ Wr, const int* __restrict__ bucket,
                           const int* __restrict__ toff, const int* __restrict__ tcnt,
                           float* __restrict__ A, int S, int V, int bv){
    int b = bv / V, v = bv - b*V;
    int t = threadIdx.x;            // t = o*8+k
    const int* bk = bucket + b*S + toff[b*V + v];
    int m = tcnt[b*V + v];
    float acc = 0.f;
    int idx = 0;
    for (; idx + 4 <= m; idx += 4){
        int c0 = bk[idx], c1 = bk[idx+1], c2 = bk[idx+2], c3 = bk[idx+3];
        acc += b2f(Wr[c0*256 + t]);
        acc += b2f(Wr[c1*256 + t]);
        acc += b2f(Wr[c2*256 + t]);
        acc += b2f(Wr[c3*256 + t]);
    }
    for (; idx < m; ++idx) acc += b2f(Wr[bk[idx]*256 + t]);
    A[b*(256*V) + t*V + v] = acc;
}

// packed2[bin][d] += 2^20 + ew, bin = (src>=MID). old -> slot within (d,bin).
__global__ void k_F1(const int* __restrict__ src, const int* __restrict__ dst,
                     const float* __restrict__ ew,
                     double* __restrict__ packed2, int* __restrict__ slot,
                     const bf16* __restrict__ Wr1, const bf16* __restrict__ Wr2,
                     const int* __restrict__ bucket_g, const int* __restrict__ toff_g,
                     const int* __restrict__ tcnt_g, float* __restrict__ Ag,
                     const int* __restrict__ bucket_l, const int* __restrict__ toff_l,
                     const int* __restrict__ tcnt_l, float* __restrict__ Al){
    int bx = blockIdx.x;
    if (bx < EDB){
        int e = bx*256 + threadIdx.x;
        int s = src[e], d = dst[e];
        int bin = (s >= MID) ? 1 : 0;
        double old = unsafeAtomicAdd(&packed2[(size_t)bin*NN + d],
                                     1048576.0 + (double)ew[e]);
        slot[e] = (int)(old * (1.0/1048576.0));
        return;
    }
    bx -= EDB;
    if (bx < NB*VG){ dev_buildA(Wr1, bucket_g, toff_g, tcnt_g, Ag, SG, VG, bx); return; }
    bx -= NB*VG;
    dev_buildA(Wr2, bucket_l, toff_l, tcnt_l, Al, SL, VL, bx);
}

// fused node_dis + gbounds + scan1 (4 nodes/thread), also cntA
__global__ void k_prep(const double* __restrict__ packed2, int* __restrict__ cnt,
                       int* __restrict__ cntA,
                       float2* __restrict__ dis12, float2* __restrict__ self12,
                       const int* __restrict__ batch, int* __restrict__ gstart,
                       int* __restrict__ bsum){
    __shared__ int sd[256];
    int t = threadIdx.x;
    int base = blockIdx.x*1024;
    int s = 0;
    #pragma unroll
    for (int j = 0; j < 4; ++j){
        int i = base + t*4 + j;
        if (i < NN){
            double pA = packed2[i];
            double pB = packed2[(size_t)NN + i];
            int cA = (int)(pA * (1.0/1048576.0));
            int cB = (int)(pB * (1.0/1048576.0));
            float w = (float)(pA - (double)cA * 1048576.0)
                    + (float)(pB - (double)cB * 1048576.0);
            int c = cA + cB;
            cnt[i] = c; cntA[i] = cA; s += c;
            float r1 = rsqrtf(w + 1.0f);
            float r2 = rsqrtf((float)c + 1.0f);
            dis12[i] = make_float2(r1, r2);
            self12[i] = make_float2(r1*r1, r2*r2);
            int pb = batch[i];
            int prev = (i == 0) ? -1 : batch[i-1];
            for (int g = prev + 1; g <= pb; ++g) gstart[g] = i;
            if (i == NN - 1){
                for (int g = pb + 1; g <= NG; ++g) gstart[g] = NN;
            }
        }
    }
    sd[t] = s; __syncthreads();
    for (int d = 128; d > 0; d >>= 1){
        if (t < d) sd[t] += sd[t+d];
        __syncthreads();
    }
    if (t == 0) bsum[blockIdx.x] = sd[0];
}

__global__ void k_scan2(int* bsum, int nb){
    if (threadIdx.x == 0 && blockIdx.x == 0){
        int run = 0;
        for (int i = 0; i < nb; ++i){ int v = bsum[i]; bsum[i] = run; run += v; }
    }
}

// offs2[d] = (A start, B start)
__global__ void k_scan3(const int* __restrict__ cnt, const int* __restrict__ cntA,
                        const int* __restrict__ bsum, int2* __restrict__ offs2){
    __shared__ int sd[256];
    int t = threadIdx.x;
    int base = blockIdx.x*1024;
    int loc[4]; int s = 0;
    #pragma unroll
    for (int j = 0; j < 4; ++j){
        int idx = base + t*4 + j;
        loc[j] = (idx < NN) ? cnt[idx] : 0;
        s += loc[j];
    }
    sd[t] = s; __syncthreads();
    for (int d = 1; d < 256; d <<= 1){
        int v = (t >= d) ? sd[t-d] : 0;
        __syncthreads();
        sd[t] += v;
        __syncthreads();
    }
    int run = bsum[blockIdx.x] + (sd[t] - s);
    #pragma unroll
    for (int j = 0; j < 4; ++j){
        int idx = base + t*4 + j;
        if (idx < NN) offs2[idx] = make_int2(run, run + cntA[idx]);
        run += loc[j];
    }
}

// ---------------- F2: edge_scatter U buildG(g) U buildG(l) U cast ----------
__device__ void dev_buildG(float (*rows)[128], const float* __restrict__ emb,
                           const float* __restrict__ W, bf16* __restrict__ G,
                           int V, int q){
    int o = q / V, mt = q - o*V;      // M = 8V, one block = 8 consecutive m
    int t = threadIdx.x;              // 256
    int j = t & 127, half = t >> 7;
    int kk[4];
    #pragma unroll
    for (int qq = 0; qq < 4; ++qq){
        int mm = half*4 + qq;
        int m = mt*8 + mm;
        int k = m / V, v = m - k*V;
        kk[qq] = k;
        rows[mm][j] = emb[v*128 + j];
    }
    __syncthreads();
    float a0=0.f, a1=0.f, a2=0.f, a3=0.f;
    const float* Wo = W + o*121*128 + j;
    for (int l = 0; l < 121; ++l){
        float w = Wo[l*128];
        a0 += rows[half*4+0][l + kk[0]] * w;
        a1 += rows[half*4+1][l + kk[1]] * w;
        a2 += rows[half*4+2][l + kk[2]] * w;
        a3 += rows[half*4+3][l + kk[3]] * w;
    }
    int M = 8*V;
    int base = (o*M + mt*8 + half*4)*128 + j;
    G[base      ] = __float2bfloat16(a0);
    G[base + 128] = __float2bfloat16(a1);
    G[base + 256] = __float2bfloat16(a2);
    G[base + 384] = __float2bfloat16(a3);
}

// epk record: (srcByteOff stride40, n1, n2, srcByteOff stride72)
__global__ void k_F2(const int* __restrict__ src, const int* __restrict__ dst,
                     const float* __restrict__ ew, const float2* __restrict__ dis12,
                     const int2* __restrict__ offs2, const int* __restrict__ slot,
                     float4* __restrict__ epk,
                     const float* __restrict__ emb1, const float* __restrict__ emb2,
                     const float* __restrict__ fcxrW, bf16* __restrict__ G1,
                     bf16* __restrict__ G2,
                     const float* __restrict__ pro_x, bf16* __restrict__ xb0){
    __shared__ float rows[8][128];
    int bx = blockIdx.x;
    if (bx < EDB){
        int e = bx*256 + threadIdx.x;
        int s = src[e], d = dst[e];
        int2 o2 = offs2[d];
        int pos = (s < MID ? o2.x : o2.y) + slot[e];
        float2 a = dis12[s], b = dis12[d];
        float4 v;
        v.x = __int_as_float(s*80);    // byte offset, stride-40 bf16
        v.y = a.x * ew[e] * b.x;       // norm layer 1
        v.z = a.y * b.y;               // norm layers 2/3
        v.w = __int_as_float(s*144);   // byte offset, stride-72 bf16
        epk[pos] = v;
        return;
    }
    bx -= EDB;
    if (bx < 32*VG){ dev_buildG(rows, emb1, fcxrW, G1, VG, bx); return; }
    bx -= 32*VG;
    if (bx < 32*VL){ dev_buildG(rows, emb2, fcxrW, G2, VL, bx); return; }
    bx -= 32*VL;
    int i = bx*256 + threadIdx.x;     // cast pro_x -> padded bf16 [NN,40]
    if (i >= NN*40) return;
    int n = i / 40, f = i - n*40;
    xb0[i] = __float2bfloat16(f < 33 ? pro_x[n*33 + f] : 0.f);
}

// ---------------- gather core (uint4 rows) ----------------
// QV uint4/row; GRP edge-groups/wave; OFF_W/N_Z pick epk lanes; SELF adds self term.
// After the xor-reduce all lanes hold the group-summed values.
template<int QV, int GRP, int OFF_W, int N_Z, int SELF>
__device__ __forceinline__ void gather8(float a[8], const bf16* __restrict__ xb,
                                        const float4* __restrict__ epk,
                                        int node, int b, int e,
                                        const float2* __restrict__ self12){
    const int LPG = 64 / GRP;
    int lane = threadIdx.x & 63;
    int grp  = lane / LPG;
    int gl   = lane % LPG;
    bool act = gl < QV;
    const char* xc = (const char*)xb;
    #pragma unroll
    for (int q = 0; q < 8; ++q) a[q] = 0.f;
    if (act){
        int fo = gl << 4;
        if (SELF && grp == 0){
            float2 sw2 = self12[node];
            float sw = N_Z ? sw2.y : sw2.x;
            uint4 u = *(const uint4*)(xc + node*(QV*16) + fo);
            a[0] = sw*blo(u.x); a[1] = sw*bhi(u.x); a[2] = sw*blo(u.y); a[3] = sw*bhi(u.y);
            a[4] = sw*blo(u.z); a[5] = sw*bhi(u.z); a[6] = sw*blo(u.w); a[7] = sw*bhi(u.w);
        }
        int p = b + grp;
        for (; p + 3*GRP < e; p += 4*GRP){
            float4 e0 = epk[p];
            float4 e1 = epk[p +   GRP];
            float4 e2 = epk[p + 2*GRP];
            float4 e3 = epk[p + 3*GRP];
            int o0 = __float_as_int(OFF_W ? e0.w : e0.x); float n0 = N_Z ? e0.z : e0.y;
            int o1 = __float_as_int(OFF_W ? e1.w : e1.x); float n1 = N_Z ? e1.z : e1.y;
            int o2 = __float_as_int(OFF_W ? e2.w : e2.x); float n2 = N_Z ? e2.z : e2.y;
            int o3 = __float_as_int(OFF_W ? e3.w : e3.x); float n3 = N_Z ? e3.z : e3.y;
            uint4 u0 = *(const uint4*)(xc + o0 + fo);
            uint4 u1 = *(const uint4*)(xc + o1 + fo);
            uint4 u2 = *(const uint4*)(xc + o2 + fo);
            uint4 u3 = *(const uint4*)(xc + o3 + fo);
            a[0] += n0*blo(u0.x); a[1] += n0*bhi(u0.x); a[2] += n0*blo(u0.y); a[3] += n0*bhi(u0.y);
            a[4] += n0*blo(u0.z); a[5] += n0*bhi(u0.z); a[6] += n0*blo(u0.w); a[7] += n0*bhi(u0.w);
            a[0] += n1*blo(u1.x); a[1] += n1*bhi(u1.x); a[2] += n1*blo(u1.y); a[3] += n1*bhi(u1.y);
            a[4] += n1*blo(u1.z); a[5] += n1*bhi(u1.z); a[6] += n1*blo(u1.w); a[7] += n1*bhi(u1.w);
            a[0] += n2*blo(u2.x); a[1] += n2*bhi(u2.x); a[2] += n2*blo(u2.y); a[3] += n2*bhi(u2.y);
            a[4] += n2*blo(u2.z); a[5] += n2*bhi(u2.z); a[6] += n2*blo(u2.w); a[7] += n2*bhi(u2.w);
            a[0] += n3*blo(u3.x); a[1] += n3*bhi(u3.x); a[2] += n3*blo(u3.y); a[3] += n3*bhi(u3.y);
            a[4] += n3*blo(u3.z); a[5] += n3*bhi(u3.z); a[6] += n3*blo(u3.w); a[7] += n3*bhi(u3.w);
        }
        for (; p < e; p += GRP){
            float4 e0 = epk[p];
            int o0 = __float_as_int(OFF_W ? e0.w : e0.x); float n0 = N_Z ? e0.z : e0.y;
            uint4 u0 = *(const uint4*)(xc + o0 + fo);
            a[0] += n0*blo(u0.x); a[1] += n0*bhi(u0.x); a[2] += n0*blo(u0.y); a[3] += n0*bhi(u0.y);
            a[4] += n0*blo(u0.z); a[5] += n0*bhi(u0.z); a[6] += n0*blo(u0.w); a[7] += n0*bhi(u0.w);
        }
    }
    #pragma unroll
    for (int m = LPG; m < 64; m <<= 1){
        #pragma unroll
        for (int q = 0; q < 8; ++q) a[q] += __shfl_xor(a[q], m);
    }
}

// L1/L2: full-range gather + GEMM epilogue.  sAgg padded (+4) vs bank conflicts.
template<int QV, int GRP, int OFF_W, int N_Z>
__global__ void k_agg_gemm(const bf16* __restrict__ xb, const float4* __restrict__ epk,
                           const int2* __restrict__ offs2, const int* __restrict__ cnt,
                           const float2* __restrict__ self12,
                           const float* __restrict__ W, const float* __restrict__ bias,
                           float* __restrict__ tout, int F, int OF){
    const int SAS = QV*8 + 4;
    __shared__ float sAgg[4*SAS];
    int wave = threadIdx.x >> 6;
    int node = blockIdx.x*4 + wave;
    int b = offs2[node].x;
    int e = b + cnt[node];
    float a[8];
    gather8<QV,GRP,OFF_W,N_Z,1>(a, xb, epk, node, b, e, self12);
    int lane = threadIdx.x & 63;
    const int LPG = 64/GRP;
    int grp = lane / LPG, gl = lane % LPG;
    if (gl < QV && grp == 0){
        float4* dst = (float4*)&sAgg[wave*SAS + gl*8];
        dst[0] = make_float4(a[0], a[1], a[2], a[3]);
        dst[1] = make_float4(a[4], a[5], a[6], a[7]);
    }
    __syncthreads();
    int i0 = blockIdx.x*4;
    for (int idx = threadIdx.x; idx < 4*OF; idx += 256){
        int r = idx / OF, j = idx - r*OF;
        float acc = bias[j];
        const float* sa = sAgg + r*SAS;
        #pragma unroll 4
        for (int f = 0; f < F; ++f) acc += sa[f] * W[f*OF + j];
        tout[(size_t)(i0+r)*OF + j] = acc;
    }
}

// gemmR for 256 threads: 8 b-rows x 256-K slice, atomic epilogue
__device__ void dev_gemmR(float* xs /* [8][256] */, int bq,
                          const float* __restrict__ Ag, const bf16* __restrict__ G1,
                          const float* __restrict__ Al, const bf16* __restrict__ G2,
                          float* __restrict__ out0){
    int kpart = bq >> 4;       // 0..69
    int bgrp  = bq & 15;
    const float* X; const bf16* G; int K, k0;
    if (kpart < 5){ X = Ag; G = G1; K = 1280;  k0 = kpart*256; }
    else          { X = Al; G = G2; K = 16640; k0 = (kpart-5)*256; }
    int b0 = bgrp*8;
    int t = threadIdx.x;
    #pragma unroll
    for (int i = 0; i < 8; ++i)
        xs[i*256 + t] = X[(b0+i)*K + k0 + t];
    __syncthreads();
    int rq = t >> 7, j = t & 127;
    const float* x0 = xs + (rq*4)*256;
    float a0=0,a1=0,a2=0,a3=0;
    const bf16* Gp = G + (size_t)k0*128 + j;
    for (int kk = 0; kk < 256; ++kk){
        float g = b2f(Gp[kk*128]);
        a0 += x0[kk]*g; a1 += x0[256+kk]*g; a2 += x0[512+kk]*g; a3 += x0[768+kk]*g;
    }
    unsafeAtomicAdd(&out0[(b0+rq*4+0)*128 + j], 0.5f*a0);
    unsafeAtomicAdd(&out0[(b0+rq*4+1)*128 + j], 0.5f*a1);
    unsafeAtomicAdd(&out0[(b0+rq*4+2)*128 + j], 0.5f*a2);
    unsafeAtomicAdd(&out0[(b0+rq*4+3)*128 + j], 0.5f*a3);
}

// L3 pass A: bin-A gather (rows < MID, 3.6MB -> L2-resident) + self -> bufP.
// Unioned with gemmR (backfill).
__global__ void k_L3A(const bf16* __restrict__ xb, const float4* __restrict__ epk,
                      const int2* __restrict__ offs2, const float2* __restrict__ self12,
                      float* __restrict__ bufP,
                      const float* __restrict__ Ag, const bf16* __restrict__ G1,
                      const float* __restrict__ Al, const bf16* __restrict__ G2,
                      float* __restrict__ out0){
    __shared__ float smem[8*256];
    int bx = blockIdx.x;
    if (bx >= AGB){ dev_gemmR(smem, bx - AGB, Ag, G1, Al, G2, out0); return; }
    int wave = threadIdx.x >> 6;
    int node = bx*4 + wave;
    int2 o2 = offs2[node];
    float a[8];
    gather8<9,4,1,1,1>(a, xb, epk, node, o2.x, o2.y, self12);
    int lane = threadIdx.x & 63;
    int grp = lane >> 4, gl = lane & 15;
    if (gl < 9 && grp == 0){
        float4* dst = (float4*)&bufP[(size_t)node*72 + gl*8];
        dst[0] = make_float4(a[0], a[1], a[2], a[3]);
        dst[1] = make_float4(a[4], a[5], a[6], a[7]);
    }
}

// L3 pass B: bin-B gather (rows >= MID) + partial + GEMM epilogue -> tout
__global__ void k_L3B(const bf16* __restrict__ xb, const float4* __restrict__ epk,
                      const int2* __restrict__ offs2, const int* __restrict__ cnt,
                      const float* __restrict__ bufP,
                      const float* __restrict__ W, const float* __restrict__ bias,
                      float* __restrict__ tout){
    const int SAS = 76;
    __shared__ float sAgg[4*SAS];
    int wave = threadIdx.x >> 6;
    int node = blockIdx.x*4 + wave;
    int2 o2 = offs2[node];
    int e = o2.x + cnt[node];
    float a[8];
    gather8<9,4,1,1,0>(a, xb, epk, node, o2.y, e, (const float2*)nullptr);
    int lane = threadIdx.x & 63;
    int grp = lane >> 4, gl = lane & 15;
    if (gl < 9 && grp == 0){
        const float4* par = (const float4*)&bufP[(size_t)node*72 + gl*8];
        float4 p0 = par[0], p1 = par[1];
        float4* dst = (float4*)&sAgg[wave*SAS + gl*8];
        dst[0] = make_float4(a[0]+p0.x, a[1]+p0.y, a[2]+p0.z, a[3]+p0.w);
        dst[1] = make_float4(a[4]+p1.x, a[5]+p1.y, a[6]+p1.z, a[7]+p1.w);
    }
    __syncthreads();
    int i0 = blockIdx.x*4;
    for (int idx = threadIdx.x; idx < 4*132; idx += 256){
        int r = idx / 132, j = idx - r*132;
        float acc = bias[j];
        const float* sa = sAgg + r*SAS;
        #pragma unroll 4
        for (int f = 0; f < 66; ++f) acc += sa[f] * W[f*132 + j];
        tout[(size_t)(i0+r)*132 + j] = acc;
    }
}

__global__ void k_bn_stats(const float* __restrict__ t, float* __restrict__ sums, int OF){
    int f = threadIdx.x;
    if (f >= OF) return;
    float s = 0.f, ss = 0.f;
    for (int i = blockIdx.x; i < NN; i += gridDim.x){
        float v = t[(size_t)i*OF + f];
        s += v; ss += v*v;
    }
    unsafeAtomicAdd(&sums[f], s);
    unsafeAtomicAdd(&sums[OF + f], ss);
}

// fused finalize+apply, flattened; padded bf16 out (stride OS)
__global__ void k_bn_apply(const float* __restrict__ t, const float* __restrict__ sums,
                           const float* __restrict__ g, const float* __restrict__ b,
                           bf16* __restrict__ xo, int OF, int OS, int total){
    int id = blockIdx.x*256 + threadIdx.x;
    if (id >= total) return;
    int i = id / OS, f = id - i*OS;
    float v = 0.f;
    if (f < OF){
        float m  = sums[f] * (1.0f/(float)NN);
        float vr = sums[OF + f] * (1.0f/(float)NN) - m*m;
        float sc = g[f] * rsqrtf(vr + 1e-5f);
        float sh = b[f] - m*sc;
        v = t[(size_t)i*OF + f] * sc + sh;
        v = v > 0.f ? v : 0.f;
    }
    xo[id] = __float2bfloat16(v);
}

// pool with BN3+relu inline, reading fp32 t; grid (NG,4) strips
__global__ void k_poolBN(const float* __restrict__ t, const float* __restrict__ sums,
                         const float* __restrict__ g, const float* __restrict__ b,
                         const int* __restrict__ gstart, float* __restrict__ poolsum){
    int gr = blockIdx.x, strip = blockIdx.y, f = threadIdx.x;
    if (f >= 132) return;
    float m  = sums[f] * (1.0f/(float)NN);
    float vr = sums[132 + f] * (1.0f/(float)NN) - m*m;
    float sc = g[f] * rsqrtf(vr + 1e-5f);
    float sh = b[f] - m*sc;
    int i0 = gstart[gr], i1 = gstart[gr+1];
    float s = 0.f;
    for (int i = i0 + strip; i < i1; i += 4){
        float v = t[(size_t)i*132 + f] * sc + sh;
        s += v > 0.f ? v : 0.f;
    }
    unsafeAtomicAdd(&poolsum[gr*132 + f], s);
}

// fused fcg1+fcg2
__global__ void k_fcgF(const float* __restrict__ poolsum, const int* __restrict__ gstart,
                       const float* __restrict__ W1, const float* __restrict__ b1,
                       const float* __restrict__ W2, const float* __restrict__ b2,
                       float* __restrict__ out){
    __shared__ float pr[132];
    __shared__ float hr[1024];
    __shared__ float part[8][128];
    int g = blockIdx.x, t = threadIdx.x;   // 1024
    if (t < 132){
        float inv = 1.0f / fmaxf((float)(gstart[g+1] - gstart[g]), 1.0f);
        pr[t] = poolsum[g*132 + t] * inv;
    }
    __syncthreads();
    float acc = b1[t];
    #pragma unroll 4
    for (int f = 0; f < 132; ++f) acc += pr[f] * W1[f*1024 + t];
    hr[t] = acc > 0.f ? acc : 0.f;
    __syncthreads();
    int ks = t >> 7, j = t & 127;
    const float* Wp = W2 + (ks*128)*128 + j;
    const float* hp = hr + ks*128;
    float a = 0.f;
    #pragma unroll 8
    for (int kk = 0; kk < 128; ++kk) a += hp[kk] * Wp[(size_t)kk*128];
    part[ks][j] = a;
    __syncthreads();
    if (t < 128){
        float s = b2[t];
        #pragma unroll
        for (int r = 0; r < 8; ++r) s += part[r][t];
        out[g*128 + t] = s;
    }
}

// ---------------- RNA bucketing (merged g/l via blockIdx.y) ----------------
#define CH 12   // ceil(S/256) for both S=3000 and 2998

__global__ void k_tok_count(const int* __restrict__ tokg, const int* __restrict__ tokl,
                            int* tcg, int* tcl){
    __shared__ int lh[VL];
    int by = blockIdx.y;
    const int* tok = by ? tokl : tokg;
    int S = by ? SL : SG, V = by ? VL : VG;
    int* tcnt = by ? tcl : tcg;
    int b = blockIdx.x / CH, c0 = (blockIdx.x % CH)*256;
    int t = threadIdx.x;
    if (t < V) lh[t] = 0;
    __syncthreads();
    int i = c0 + t;
    if (i < S) atomicAdd(&lh[tok[b*S + i]], 1);
    __syncthreads();
    if (t < V && lh[t] > 0) atomicAdd(&tcnt[b*V + t], lh[t]);
}

__global__ void k_tok_off(const int* __restrict__ tcg, const int* __restrict__ tcl,
                          int* tog, int* tol){
    int by = blockIdx.y;
    const int* tcnt = by ? tcl : tcg;
    int* toff = by ? tol : tog;
    int V = by ? VL : VG;
    int b = blockIdx.x;
    if (threadIdx.x != 0) return;
    int run = 0;
    for (int v = 0; v < V; ++v){ toff[b*V + v] = run; run += tcnt[b*V + v]; }
}

__global__ void k_tok_scatter(const int* __restrict__ tokg, const int* __restrict__ tokl,
                              const int* __restrict__ tog, const int* __restrict__ tol,
                              int* tcur_g, int* tcur_l,
                              int* __restrict__ bucket_g, int* __restrict__ bucket_l){
    __shared__ int lh[VL], lbase[VL], lcur[VL];
    int by = blockIdx.y;
    const int* tok = by ? tokl : tokg;
    const int* toff = by ? tol : tog;
    int* tcur = by ? tcur_l : tcur_g;
    int* bucket = by ? bucket_l : bucket_g;
    int S = by ? SL : SG, V = by ? VL : VG;
    int b = blockIdx.x / CH, c0 = (blockIdx.x % CH)*256;
    int t = threadIdx.x;
    if (t < V){ lh[t] = 0; lcur[t] = 0; }
    __syncthreads();
    int i = c0 + t;
    int v = -1;
    if (i < S){ v = tok[b*S + i]; atomicAdd(&lh[v], 1); }
    __syncthreads();
    if (t < V && lh[t] > 0) lbase[t] = atomicAdd(&tcur[b*V + t], lh[t]);
    __syncthreads();
    if (i < S){
        int p = lbase[v] + atomicAdd(&lcur[v], 1);
        bucket[b*S + toff[b*V + v] + p] = i;
    }
}

// merged transpose: Wr[c*256 + o*8+k] = bf16(W[(o*S+c)*8+k])
__global__ void k_transposeW(const float* __restrict__ W1, const float* __restrict__ W2,
                             bf16* __restrict__ Wr1, bf16* __restrict__ Wr2){
    int c = blockIdx.x, t = threadIdx.x;
    const float* W; bf16* Wr; int S;
    if (c < SG){ W = W1; Wr = Wr1; S = SG; }
    else { c -= SG; W = W2; Wr = Wr2; S = SL; }
    Wr[c*256 + t] = __float2bfloat16(W[((t >> 3)*S + c)*8 + (t & 7)]);
}

__global__ void k_bias0_acc(const float* __restrict__ W, const float* __restrict__ cb1,
                            const float* __restrict__ cb2, float* __restrict__ bias0){
    int o = blockIdx.x, j = threadIdx.x;
    float s = 0.f;
    const float* Wo = W + o*121*128 + j;
    for (int l = 0; l < 121; ++l) s += Wo[l*128];
    unsafeAtomicAdd(&bias0[j], 0.5f * (cb1[o] + cb2[o]) * s);
}

__global__ void k_init_out0(const float* __restrict__ fcxrb, const float* __restrict__ bias0,
                            float* __restrict__ out0){
    int j = threadIdx.x;
    out0[blockIdx.x*128 + j] = fcxrb[j] + bias0[j];
}

extern "C" void kernel_launch(void* const* d_in, const int* in_sizes, int n_in,
                              void* d_out, int out_size, void* d_ws, size_t ws_size,
                              hipStream_t stream)
{
    (void)in_sizes; (void)n_in; (void)out_size; (void)ws_size;

    const float* pro_x  = (const float*)d_in[0];
    const int*   eidx   = (const int*)  d_in[1];
    const float* ew     = (const float*)d_in[2];
    const int*   pbatch = (const int*)  d_in[3];
    const int*   rna_g  = (const int*)  d_in[4];
    const int*   rna_l  = (const int*)  d_in[5];
    const float* emb1   = (const float*)d_in[6];
    const float* emb2   = (const float*)d_in[7];
    const float* convW1 = (const float*)d_in[8];
    const float* convb1 = (const float*)d_in[9];
    const float* convW2 = (const float*)d_in[10];
    const float* convb2 = (const float*)d_in[11];
    const float* fcxrW  = (const float*)d_in[12];
    const float* fcxrb  = (const float*)d_in[13];
    const float* g1W = (const float*)d_in[14];
    const float* g1b = (const float*)d_in[15];
    const float* g2W = (const float*)d_in[16];
    const float* g2b = (const float*)d_in[17];
    const float* g3W = (const float*)d_in[18];
    const float* g3b = (const float*)d_in[19];
    const float* bn1g = (const float*)d_in[20];
    const float* bn1b = (const float*)d_in[21];
    const float* bn2g = (const float*)d_in[22];
    const float* bn2b = (const float*)d_in[23];
    const float* bn3g = (const float*)d_in[24];
    const float* bn3b = (const float*)d_in[25];
    const float* fcg1W = (const float*)d_in[26];
    const float* fcg1b = (const float*)d_in[27];
    const float* fcg2W = (const float*)d_in[28];
    const float* fcg2b = (const float*)d_in[29];

    const int* e_src = eidx;
    const int* e_dst = eidx + NE;

    char* base = (char*)d_ws;
    size_t off = 0;
    auto alloc = [&](size_t bytes)->char*{
        off = (off + 255) & ~(size_t)255;
        char* p = base + off; off += bytes; return p;
    };

    // ---- zero zone (single memset) ----
    double* packed2 = (double*)alloc((size_t)2*NN*8);
    int*   tcnt_g  = (int*)  alloc(NB*VG*4);
    int*   tcur_g  = (int*)  alloc(NB*VG*4);
    int*   tcnt_l  = (int*)  alloc(NB*VL*4);
    int*   tcur_l  = (int*)  alloc(NB*VL*4);
    float* bnsum1  = (float*)alloc(2*33*4);
    float* bnsum2  = (float*)alloc(2*66*4);
    float* bnsum3  = (float*)alloc(2*132*4);
    float* poolsum = (float*)alloc(NG*132*4);
    float* bias0   = (float*)alloc(128*4);
    size_t zero_bytes = (off + 255) & ~(size_t)255;

    // ---- persistent buffers ----
    int*    cnt    = (int*)   alloc(NN*4);
    int*    cntA   = (int*)   alloc(NN*4);
    float2* dis12  = (float2*)alloc(NN*8);
    float2* self12 = (float2*)alloc(NN*8);
    int2*   offs2  = (int2*)  alloc(NN*8);
    int*    bsum   = (int*)   alloc(64*4);
    int*    gstart = (int*)   alloc((NG+1)*4);
    float4* epk    = (float4*)alloc((size_t)NE*16);
    float*  bufB   = (float*) alloc((size_t)NN*132*4);     // t (max OF=132)
    char*   xbArea = (char*)  alloc((size_t)NN*72*4);      // slot / stride-40 feats / bufP
    bf16*   xbB    = (bf16*)  alloc((size_t)NN*72*2);      // stride-72 features
    float*  Ag     = (float*) alloc((size_t)NB*256*VG*4);  // persistent: read in k_L3A
    float*  Al     = (float*) alloc((size_t)NB*256*VL*4);
    bf16*   G1     = (bf16*)  alloc((size_t)32*8*VG*128*2);
    bf16*   G2     = (bf16*)  alloc((size_t)32*8*VL*128*2);

    // xbArea phases (sequential, same stream):
    //  slot (NE*4=6.4MB, F1->F2) -> xbA stride-40 feats (4MB, bn_apply1->L2 agg)
    //  -> bufP fp32 partials (14.4MB, L3A->L3B)
    int*   slot = (int*)xbArea;
    bf16*  xbA  = (bf16*)xbArea;
    float* bufP = (float*)xbArea;
    // xb0 (stride-40 cast) aliases xbB (first written by L2 bn_apply)
    bf16* xb0  = (bf16*)xbB;

    float* out0 = (float*)d_out;          // xc_rna
    float* out1 = (float*)d_out + 16384;  // xp_out

    // ---- RNA bucketing scratch aliased onto bufB (consumed by F1/F2,
    // which complete before L1 agg_gemm writes bufB) ----
    char* rb = (char*)bufB;
    size_t ro = 0;
    auto ralloc = [&](size_t bytes)->char*{
        ro = (ro + 255) & ~(size_t)255;
        char* p = rb + ro; ro += bytes; return p;
    };
    int* toff_g   = (int*)ralloc(NB*VG*4);
    int* toff_l   = (int*)ralloc(NB*VL*4);
    int* bucket_g = (int*)ralloc((size_t)NB*SG*4);
    int* bucket_l = (int*)ralloc((size_t)NB*SL*4);
    bf16* Wr1     = (bf16*)ralloc((size_t)SG*256*2);
    bf16* Wr2     = (bf16*)ralloc((size_t)SL*256*2);

    hipMemsetAsync(d_ws, 0, zero_bytes, stream);

    // ---- RNA bucketing + weight prep ----
    k_tok_count<<<dim3(NB*CH,2), 256, 0, stream>>>(rna_g, rna_l, tcnt_g, tcnt_l);
    k_tok_off<<<dim3(NB,2), 64, 0, stream>>>(tcnt_g, tcnt_l, toff_g, toff_l);
    k_tok_scatter<<<dim3(NB*CH,2), 256, 0, stream>>>(rna_g, rna_l, toff_g, toff_l,
                                                     tcur_g, tcur_l, bucket_g, bucket_l);
    k_transposeW<<<SG+SL, 256, 0, stream>>>(convW1, convW2, Wr1, Wr2);
    k_bias0_acc<<<32, 128, 0, stream>>>(fcxrW, convb1, convb2, bias0);
    k_init_out0<<<NB, 128, 0, stream>>>(fcxrb, bias0, out0);

    // ---- F1: src-binned edge histogram co-dispatched with buildA ----
    k_F1<<<EDB + NB*VG + NB*VL, 256, 0, stream>>>(e_src, e_dst, ew, packed2, slot,
                                                  Wr1, Wr2,
                                                  bucket_g, toff_g, tcnt_g, Ag,
                                                  bucket_l, toff_l, tcnt_l, Al);
    k_prep<<<49, 256, 0, stream>>>(packed2, cnt, cntA, dis12, self12,
                                   pbatch, gstart, bsum);
    k_scan2<<<1, 64, 0, stream>>>(bsum, 49);
    k_scan3<<<49, 256, 0, stream>>>(cnt, cntA, bsum, offs2);

    // ---- F2: edge scatter co-dispatched with buildG + cast ----
    k_F2<<<EDB + 32*VG + 32*VL + (NN*40+255)/256, 256, 0, stream>>>(
        e_src, e_dst, ew, dis12, offs2, slot, epk,
        emb1, emb2, fcxrW, G1, G2, pro_x, xb0);

    // ---- GCN layer 1 (33 -> 33), input stride 40 ----
    k_agg_gemm<5,8,0,0><<<AGB, 256, 0, stream>>>(xb0, epk, offs2, cnt, self12,
                                                 g1W, g1b, bufB, 33, 33);
    k_bn_stats<<<256, 64, 0, stream>>>(bufB, bnsum1, 33);
    k_bn_apply<<<(NN*40+255)/256, 256, 0, stream>>>(bufB, bnsum1, bn1g, bn1b,
                                                    xbA, 33, 40, NN*40);

    // ---- GCN layer 2 (33 -> 66), output stride 72 ----
    k_agg_gemm<5,8,0,1><<<AGB, 256, 0, stream>>>(xbA, epk, offs2, cnt, self12,
                                                 g2W, g2b, bufB, 33, 66);
    k_bn_stats<<<256, 128, 0, stream>>>(bufB, bnsum2, 66);
    k_bn_apply<<<(NN*72+255)/256, 256, 0, stream>>>(bufB, bnsum2, bn2g, bn2b,
                                                    xbB, 66, 72, NN*72);

    // ---- GCN layer 3 (66 -> 132): two src-binned passes (L2-resident rows) ----
    k_L3A<<<AGB + 1120, 256, 0, stream>>>(xbB, epk, offs2, self12, bufP,
                                          Ag, G1, Al, G2, out0);
    k_L3B<<<AGB, 256, 0, stream>>>(xbB, epk, offs2, cnt, bufP, g3W, g3b, bufB);
    k_bn_stats<<<256, 192, 0, stream>>>(bufB, bnsum3, 132);

    // ---- pool (BN3+relu inline) + fused head ----
    k_poolBN<<<dim3(NG,4), 192, 0, stream>>>(bufB, bnsum3, bn3g, bn3b, gstart, poolsum);
    k_fcgF<<<NG, 1024, 0, stream>>>(poolsum, gstart, fcg1W, fcg1b, fcg2W, fcg2b, out1);
}

// Round 12
// 768.437 us; speedup vs baseline: 1.1229x; 1.1229x over previous
//
#include <hip/hip_runtime.h>
#include <hip/hip_bf16.h>

typedef __hip_bfloat16 bf16;

#define NN 50000      // nodes
#define NE 1600000    // edges (= 6250*256 exactly)
#define NG 128        // graphs
#define NB 128        // rna batch
#define SG 3000       // global seq (channels)
#define SL 2998       // local seq
#define VG 5          // global vocab
#define VL 65         // local vocab
#define EDB 6250      // edge blocks (NE/256)
#define AGB 12500     // agg blocks (NN/4)

__device__ __forceinline__ float b2f(bf16 x){ return __bfloat162float(x); }
__device__ __forceinline__ float blo(unsigned u){ return __uint_as_float(u << 16); }
__device__ __forceinline__ float bhi(unsigned u){ return __uint_as_float(u & 0xffff0000u); }

// ---------------- F1: edge_deg  U  buildA(g)  U  buildA(l) ----------------
__device__ void dev_buildA(const bf16* __restrict__ Wr, const int* __restrict__ bucket,
                           const int* __restrict__ toff, const int* __restrict__ tcnt,
                           float* __restrict__ A, int S, int V, int bv){
    int b = bv / V, v = bv - b*V;
    int t = threadIdx.x;            // t = o*8+k
    const int* bk = bucket + b*S + toff[b*V + v];
    int m = tcnt[b*V + v];
    float acc = 0.f;
    int idx = 0;
    for (; idx + 4 <= m; idx += 4){
        int c0 = bk[idx], c1 = bk[idx+1], c2 = bk[idx+2], c3 = bk[idx+3];
        acc += b2f(Wr[c0*256 + t]);
        acc += b2f(Wr[c1*256 + t]);
        acc += b2f(Wr[c2*256 + t]);
        acc += b2f(Wr[c3*256 + t]);
    }
    for (; idx < m; ++idx) acc += b2f(Wr[bk[idx]*256 + t]);
    A[b*(256*V) + t*V + v] = acc;
}

__global__ void k_F1(const int* __restrict__ dst, const float* __restrict__ ew,
                     double* __restrict__ packed, int* __restrict__ slot,
                     const bf16* __restrict__ Wr1, const bf16* __restrict__ Wr2,
                     const int* __restrict__ bucket_g, const int* __restrict__ toff_g,
                     const int* __restrict__ tcnt_g, float* __restrict__ Ag,
                     const int* __restrict__ bucket_l, const int* __restrict__ toff_l,
                     const int* __restrict__ tcnt_l, float* __restrict__ Al){
    int bx = blockIdx.x;
    if (bx < EDB){
        int e = bx*256 + threadIdx.x;
        double old = unsafeAtomicAdd(&packed[dst[e]], 1048576.0 + (double)ew[e]);
        slot[e] = (int)(old * (1.0/1048576.0));
        return;
    }
    bx -= EDB;
    if (bx < NB*VG){ dev_buildA(Wr1, bucket_g, toff_g, tcnt_g, Ag, SG, VG, bx); return; }
    bx -= NB*VG;
    dev_buildA(Wr2, bucket_l, toff_l, tcnt_l, Al, SL, VL, bx);
}

// fused node_dis + gbounds + scan1: grid 49 x 256, 4 nodes/thread
__global__ void k_prep(const double* __restrict__ packed, int* __restrict__ cnt,
                       float2* __restrict__ dis12, float2* __restrict__ self12,
                       const int* __restrict__ batch, int* __restrict__ gstart,
                       int* __restrict__ bsum){
    __shared__ int sd[256];
    int t = threadIdx.x;
    int base = blockIdx.x*1024;
    int s = 0;
    #pragma unroll
    for (int j = 0; j < 4; ++j){
        int i = base + t*4 + j;
        if (i < NN){
            double p = packed[i];
            int c = (int)(p * (1.0/1048576.0));
            float w = (float)(p - (double)c * 1048576.0);
            cnt[i] = c; s += c;
            float r1 = rsqrtf(w + 1.0f);
            float r2 = rsqrtf((float)c + 1.0f);
            dis12[i] = make_float2(r1, r2);
            self12[i] = make_float2(r1*r1, r2*r2);
            int pb = batch[i];
            int prev = (i == 0) ? -1 : batch[i-1];
            for (int g = prev + 1; g <= pb; ++g) gstart[g] = i;
            if (i == NN - 1){
                for (int g = pb + 1; g <= NG; ++g) gstart[g] = NN;
            }
        }
    }
    sd[t] = s; __syncthreads();
    for (int d = 128; d > 0; d >>= 1){
        if (t < d) sd[t] += sd[t+d];
        __syncthreads();
    }
    if (t == 0) bsum[blockIdx.x] = sd[0];
}

__global__ void k_scan2(int* bsum, int nb){
    if (threadIdx.x == 0 && blockIdx.x == 0){
        int run = 0;
        for (int i = 0; i < nb; ++i){ int v = bsum[i]; bsum[i] = run; run += v; }
    }
}

__global__ void k_scan3(const int* __restrict__ cnt, const int* __restrict__ bsum,
                        int* __restrict__ offs){
    __shared__ int sd[256];
    int t = threadIdx.x;
    int base = blockIdx.x*1024;
    int loc[4]; int s = 0;
    #pragma unroll
    for (int j = 0; j < 4; ++j){
        int idx = base + t*4 + j;
        loc[j] = (idx < NN) ? cnt[idx] : 0;
        s += loc[j];
    }
    sd[t] = s; __syncthreads();
    for (int d = 1; d < 256; d <<= 1){
        int v = (t >= d) ? sd[t-d] : 0;
        __syncthreads();
        sd[t] += v;
        __syncthreads();
    }
    int run = bsum[blockIdx.x] + (sd[t] - s);
    #pragma unroll
    for (int j = 0; j < 4; ++j){
        int idx = base + t*4 + j;
        if (idx < NN) offs[idx] = run;
        run += loc[j];
    }
}

// ---------------- F2: edge_scatter U buildG(g) U buildG(l) U cast ----------
__device__ void dev_buildG(float (*rows)[128], const float* __restrict__ emb,
                           const float* __restrict__ W, bf16* __restrict__ G,
                           int V, int q){
    int o = q / V, mt = q - o*V;      // M = 8V, one block = 8 consecutive m
    int t = threadIdx.x;              // 256
    int j = t & 127, half = t >> 7;
    int kk[4];
    #pragma unroll
    for (int qq = 0; qq < 4; ++qq){
        int mm = half*4 + qq;
        int m = mt*8 + mm;
        int k = m / V, v = m - k*V;
        kk[qq] = k;
        rows[mm][j] = emb[v*128 + j];
    }
    __syncthreads();
    float a0=0.f, a1=0.f, a2=0.f, a3=0.f;
    const float* Wo = W + o*121*128 + j;
    for (int l = 0; l < 121; ++l){
        float w = Wo[l*128];
        a0 += rows[half*4+0][l + kk[0]] * w;
        a1 += rows[half*4+1][l + kk[1]] * w;
        a2 += rows[half*4+2][l + kk[2]] * w;
        a3 += rows[half*4+3][l + kk[3]] * w;
    }
    int M = 8*V;
    int base = (o*M + mt*8 + half*4)*128 + j;
    G[base      ] = __float2bfloat16(a0);
    G[base + 128] = __float2bfloat16(a1);
    G[base + 256] = __float2bfloat16(a2);
    G[base + 384] = __float2bfloat16(a3);
}

// epk record: (srcByteOff stride40, n1, n2, srcByteOff stride72)
__global__ void k_F2(const int* __restrict__ src, const int* __restrict__ dst,
                     const float* __restrict__ ew, const float2* __restrict__ dis12,
                     const int* __restrict__ offs, const int* __restrict__ slot,
                     float4* __restrict__ epk,
                     const float* __restrict__ emb1, const float* __restrict__ emb2,
                     const float* __restrict__ fcxrW, bf16* __restrict__ G1,
                     bf16* __restrict__ G2,
                     const float* __restrict__ pro_x, bf16* __restrict__ xb0){
    __shared__ float rows[8][128];
    int bx = blockIdx.x;
    if (bx < EDB){
        int e = bx*256 + threadIdx.x;
        int s = src[e], d = dst[e];
        int pos = offs[d] + slot[e];
        float2 a = dis12[s], b = dis12[d];
        float4 v;
        v.x = __int_as_float(s*80);    // byte offset, stride-40 bf16
        v.y = a.x * ew[e] * b.x;       // norm layer 1
        v.z = a.y * b.y;               // norm layers 2/3
        v.w = __int_as_float(s*144);   // byte offset, stride-72 bf16
        epk[pos] = v;
        return;
    }
    bx -= EDB;
    if (bx < 32*VG){ dev_buildG(rows, emb1, fcxrW, G1, VG, bx); return; }
    bx -= 32*VG;
    if (bx < 32*VL){ dev_buildG(rows, emb2, fcxrW, G2, VL, bx); return; }
    bx -= 32*VL;
    int i = bx*256 + threadIdx.x;     // cast pro_x -> padded bf16 [NN,40]
    if (i >= NN*40) return;
    int n = i / 40, f = i - n*40;
    xb0[i] = __float2bfloat16(f < 33 ? pro_x[n*33 + f] : 0.f);
}

// ---------------- fused aggregate + GEMM (uint4 rows) ----------------
// QV = uint4s per padded row; GRP edge-groups per wave; OFF_W/N_Z pick epk lanes.
// Epilogue: thread j computes all 4 nodes' output j (1 W-load per 4 FMA;
// sAgg reads are LDS broadcasts).
template<int QV, int GRP, int OFF_W, int N_Z>
__device__ void dev_agg(float* sAgg /* [4][QV*8] */,
                        const bf16* __restrict__ xb, const float4* __restrict__ epk,
                        const int* __restrict__ offs, const int* __restrict__ cnt,
                        const float2* __restrict__ self12,
                        const float* __restrict__ W, const float* __restrict__ bias,
                        float* __restrict__ tout, int F, int OF, int bx){
    const int LPG = 64 / GRP;
    int wave = threadIdx.x >> 6;
    int node = bx*4 + wave;
    int lane = threadIdx.x & 63;
    int grp  = lane / LPG;
    int gl   = lane % LPG;
    bool act = gl < QV;
    const char* xc = (const char*)xb;
    float a0=0,a1=0,a2=0,a3=0,a4=0,a5=0,a6=0,a7=0;
    int b = offs[node], e = b + cnt[node];
    if (act){
        int fo = gl << 4;   // lane byte offset within row
        if (grp == 0){
            float2 sw2 = self12[node];
            float sw = N_Z ? sw2.y : sw2.x;
            uint4 u = *(const uint4*)(xc + node*(QV*16) + fo);
            a0 = sw*blo(u.x); a1 = sw*bhi(u.x); a2 = sw*blo(u.y); a3 = sw*bhi(u.y);
            a4 = sw*blo(u.z); a5 = sw*bhi(u.z); a6 = sw*blo(u.w); a7 = sw*bhi(u.w);
        }
        int p = b + grp;
        for (; p + 3*GRP < e; p += 4*GRP){
            float4 e0 = epk[p];
            float4 e1 = epk[p +   GRP];
            float4 e2 = epk[p + 2*GRP];
            float4 e3 = epk[p + 3*GRP];
            int o0 = __float_as_int(OFF_W ? e0.w : e0.x); float n0 = N_Z ? e0.z : e0.y;
            int o1 = __float_as_int(OFF_W ? e1.w : e1.x); float n1 = N_Z ? e1.z : e1.y;
            int o2 = __float_as_int(OFF_W ? e2.w : e2.x); float n2 = N_Z ? e2.z : e2.y;
            int o3 = __float_as_int(OFF_W ? e3.w : e3.x); float n3 = N_Z ? e3.z : e3.y;
            uint4 u0 = *(const uint4*)(xc + o0 + fo);
            uint4 u1 = *(const uint4*)(xc + o1 + fo);
            uint4 u2 = *(const uint4*)(xc + o2 + fo);
            uint4 u3 = *(const uint4*)(xc + o3 + fo);
            a0 += n0*blo(u0.x); a1 += n0*bhi(u0.x); a2 += n0*blo(u0.y); a3 += n0*bhi(u0.y);
            a4 += n0*blo(u0.z); a5 += n0*bhi(u0.z); a6 += n0*blo(u0.w); a7 += n0*bhi(u0.w);
            a0 += n1*blo(u1.x); a1 += n1*bhi(u1.x); a2 += n1*blo(u1.y); a3 += n1*bhi(u1.y);
            a4 += n1*blo(u1.z); a5 += n1*bhi(u1.z); a6 += n1*blo(u1.w); a7 += n1*bhi(u1.w);
            a0 += n2*blo(u2.x); a1 += n2*bhi(u2.x); a2 += n2*blo(u2.y); a3 += n2*bhi(u2.y);
            a4 += n2*blo(u2.z); a5 += n2*bhi(u2.z); a6 += n2*blo(u2.w); a7 += n2*bhi(u2.w);
            a0 += n3*blo(u3.x); a1 += n3*bhi(u3.x); a2 += n3*blo(u3.y); a3 += n3*bhi(u3.y);
            a4 += n3*blo(u3.z); a5 += n3*bhi(u3.z); a6 += n3*blo(u3.w); a7 += n3*bhi(u3.w);
        }
        for (; p < e; p += GRP){
            float4 e0 = epk[p];
            int o0 = __float_as_int(OFF_W ? e0.w : e0.x); float n0 = N_Z ? e0.z : e0.y;
            uint4 u0 = *(const uint4*)(xc + o0 + fo);
            a0 += n0*blo(u0.x); a1 += n0*bhi(u0.x); a2 += n0*blo(u0.y); a3 += n0*bhi(u0.y);
            a4 += n0*blo(u0.z); a5 += n0*bhi(u0.z); a6 += n0*blo(u0.w); a7 += n0*bhi(u0.w);
        }
    }
    #pragma unroll
    for (int m = LPG; m < 64; m <<= 1){
        a0 += __shfl_xor(a0, m); a1 += __shfl_xor(a1, m);
        a2 += __shfl_xor(a2, m); a3 += __shfl_xor(a3, m);
        a4 += __shfl_xor(a4, m); a5 += __shfl_xor(a5, m);
        a6 += __shfl_xor(a6, m); a7 += __shfl_xor(a7, m);
    }
    if (act && grp == 0){
        float4* dst = (float4*)&sAgg[wave*(QV*8) + gl*8];
        dst[0] = make_float4(a0, a1, a2, a3);
        dst[1] = make_float4(a4, a5, a6, a7);
    }
    __syncthreads();
    int i0 = bx*4;
    int j = threadIdx.x;
    if (j < OF){
        float c0 = bias[j], c1 = c0, c2 = c0, c3 = c0;
        const float* Wj = W + j;
        const float* s0 = sAgg;
        const float* s1 = sAgg + QV*8;
        const float* s2 = sAgg + 2*QV*8;
        const float* s3 = sAgg + 3*QV*8;
        #pragma unroll 4
        for (int f = 0; f < F; ++f){
            float w = Wj[f*OF];
            c0 += s0[f]*w; c1 += s1[f]*w; c2 += s2[f]*w; c3 += s3[f]*w;
        }
        tout[(size_t)(i0+0)*OF + j] = c0;
        tout[(size_t)(i0+1)*OF + j] = c1;
        tout[(size_t)(i0+2)*OF + j] = c2;
        tout[(size_t)(i0+3)*OF + j] = c3;
    }
}

template<int QV, int GRP, int OFF_W, int N_Z>
__global__ void k_agg_gemm(const bf16* __restrict__ xb, const float4* __restrict__ epk,
                           const int* __restrict__ offs, const int* __restrict__ cnt,
                           const float2* __restrict__ self12,
                           const float* __restrict__ W, const float* __restrict__ bias,
                           float* __restrict__ tout, int F, int OF){
    __shared__ float sAgg[4*QV*8];
    dev_agg<QV,GRP,OFF_W,N_Z>(sAgg, xb, epk, offs, cnt, self12, W, bias,
                              tout, F, OF, blockIdx.x);
}

// gemmR for 256 threads: 8 b-rows x 256-K slice, atomic epilogue
__device__ void dev_gemmR(float* xs /* [8][256] */, int bq,
                          const float* __restrict__ Ag, const bf16* __restrict__ G1,
                          const float* __restrict__ Al, const bf16* __restrict__ G2,
                          float* __restrict__ out0){
    int kpart = bq >> 4;       // 0..69
    int bgrp  = bq & 15;
    const float* X; const bf16* G; int K, k0;
    if (kpart < 5){ X = Ag; G = G1; K = 1280;  k0 = kpart*256; }
    else          { X = Al; G = G2; K = 16640; k0 = (kpart-5)*256; }
    int b0 = bgrp*8;
    int t = threadIdx.x;
    #pragma unroll
    for (int i = 0; i < 8; ++i)
        xs[i*256 + t] = X[(b0+i)*K + k0 + t];
    __syncthreads();
    int rq = t >> 7, j = t & 127;
    const float* x0 = xs + (rq*4)*256;
    float a0=0,a1=0,a2=0,a3=0;
    const bf16* Gp = G + (size_t)k0*128 + j;
    for (int kk = 0; kk < 256; ++kk){
        float g = b2f(Gp[kk*128]);
        a0 += x0[kk]*g; a1 += x0[256+kk]*g; a2 += x0[512+kk]*g; a3 += x0[768+kk]*g;
    }
    unsafeAtomicAdd(&out0[(b0+rq*4+0)*128 + j], 0.5f*a0);
    unsafeAtomicAdd(&out0[(b0+rq*4+1)*128 + j], 0.5f*a1);
    unsafeAtomicAdd(&out0[(b0+rq*4+2)*128 + j], 0.5f*a2);
    unsafeAtomicAdd(&out0[(b0+rq*4+3)*128 + j], 0.5f*a3);
}

// L3 aggregate+gemm  U  gemmR (RNA head backfills L3's latency stalls)
__global__ void k_L3(const bf16* __restrict__ xb, const float4* __restrict__ epk,
                     const int* __restrict__ offs, const int* __restrict__ cnt,
                     const float2* __restrict__ self12,
                     const float* __restrict__ W, const float* __restrict__ bias,
                     float* __restrict__ tout,
                     const float* __restrict__ Ag, const bf16* __restrict__ G1,
                     const float* __restrict__ Al, const bf16* __restrict__ G2,
                     float* __restrict__ out0){
    __shared__ float smem[8*256];
    int bx = blockIdx.x;
    if (bx < AGB){
        dev_agg<9,4,1,1>(smem, xb, epk, offs, cnt, self12, W, bias, tout, 66, 132, bx);
    } else {
        dev_gemmR(smem, bx - AGB, Ag, G1, Al, G2, out0);
    }
}

__global__ void k_bn_stats(const float* __restrict__ t, float* __restrict__ sums, int OF){
    int f = threadIdx.x;
    if (f >= OF) return;
    float s = 0.f, ss = 0.f;
    for (int i = blockIdx.x; i < NN; i += gridDim.x){
        float v = t[(size_t)i*OF + f];
        s += v; ss += v*v;
    }
    unsafeAtomicAdd(&sums[f], s);
    unsafeAtomicAdd(&sums[OF + f], ss);
}

// fused finalize+apply, flattened; padded bf16 out (stride OS)
__global__ void k_bn_apply(const float* __restrict__ t, const float* __restrict__ sums,
                           const float* __restrict__ g, const float* __restrict__ b,
                           bf16* __restrict__ xo, int OF, int OS, int total){
    int id = blockIdx.x*256 + threadIdx.x;
    if (id >= total) return;
    int i = id / OS, f = id - i*OS;
    float v = 0.f;
    if (f < OF){
        float m  = sums[f] * (1.0f/(float)NN);
        float vr = sums[OF + f] * (1.0f/(float)NN) - m*m;
        float sc = g[f] * rsqrtf(vr + 1e-5f);
        float sh = b[f] - m*sc;
        v = t[(size_t)i*OF + f] * sc + sh;
        v = v > 0.f ? v : 0.f;
    }
    xo[id] = __float2bfloat16(v);
}

// pool with BN3+relu inline, reading fp32 t; grid (NG,4) strips
__global__ void k_poolBN(const float* __restrict__ t, const float* __restrict__ sums,
                         const float* __restrict__ g, const float* __restrict__ b,
                         const int* __restrict__ gstart, float* __restrict__ poolsum){
    int gr = blockIdx.x, strip = blockIdx.y, f = threadIdx.x;
    if (f >= 132) return;
    float m  = sums[f] * (1.0f/(float)NN);
    float vr = sums[132 + f] * (1.0f/(float)NN) - m*m;
    float sc = g[f] * rsqrtf(vr + 1e-5f);
    float sh = b[f] - m*sc;
    int i0 = gstart[gr], i1 = gstart[gr+1];
    float s = 0.f;
    for (int i = i0 + strip; i < i1; i += 4){
        float v = t[(size_t)i*132 + f] * sc + sh;
        s += v > 0.f ? v : 0.f;
    }
    unsafeAtomicAdd(&poolsum[gr*132 + f], s);
}

// fused fcg1+fcg2: block g computes h[g,:] in LDS then the 128-out GEMV
__global__ void k_fcgF(const float* __restrict__ poolsum, const int* __restrict__ gstart,
                       const float* __restrict__ W1, const float* __restrict__ b1,
                       const float* __restrict__ W2, const float* __restrict__ b2,
                       float* __restrict__ out){
    __shared__ float pr[132];
    __shared__ float hr[1024];
    __shared__ float part[8][128];
    int g = blockIdx.x, t = threadIdx.x;   // 1024
    if (t < 132){
        float inv = 1.0f / fmaxf((float)(gstart[g+1] - gstart[g]), 1.0f);
        pr[t] = poolsum[g*132 + t] * inv;
    }
    __syncthreads();
    float acc = b1[t];
    #pragma unroll 4
    for (int f = 0; f < 132; ++f) acc += pr[f] * W1[f*1024 + t];
    hr[t] = acc > 0.f ? acc : 0.f;
    __syncthreads();
    int ks = t >> 7, j = t & 127;
    const float* Wp = W2 + (ks*128)*128 + j;
    const float* hp = hr + ks*128;
    float a = 0.f;
    #pragma unroll 8
    for (int kk = 0; kk < 128; ++kk) a += hp[kk] * Wp[(size_t)kk*128];
    part[ks][j] = a;
    __syncthreads();
    if (t < 128){
        float s = b2[t];
        #pragma unroll
        for (int r = 0; r < 8; ++r) s += part[r][t];
        out[g*128 + t] = s;
    }
}

// ---------------- RNA bucketing (merged g/l via blockIdx.y) ----------------
#define CH 12   // ceil(S/256) for both S=3000 and 2998

__global__ void k_tok_count(const int* __restrict__ tokg, const int* __restrict__ tokl,
                            int* tcg, int* tcl){
    __shared__ int lh[VL];
    int by = blockIdx.y;
    const int* tok = by ? tokl : tokg;
    int S = by ? SL : SG, V = by ? VL : VG;
    int* tcnt = by ? tcl : tcg;
    int b = blockIdx.x / CH, c0 = (blockIdx.x % CH)*256;
    int t = threadIdx.x;
    if (t < V) lh[t] = 0;
    __syncthreads();
    int i = c0 + t;
    if (i < S) atomicAdd(&lh[tok[b*S + i]], 1);
    __syncthreads();
    if (t < V && lh[t] > 0) atomicAdd(&tcnt[b*V + t], lh[t]);
}

__global__ void k_tok_off(const int* __restrict__ tcg, const int* __restrict__ tcl,
                          int* tog, int* tol){
    int by = blockIdx.y;
    const int* tcnt = by ? tcl : tcg;
    int* toff = by ? tol : tog;
    int V = by ? VL : VG;
    int b = blockIdx.x;
    if (threadIdx.x != 0) return;
    int run = 0;
    for (int v = 0; v < V; ++v){ toff[b*V + v] = run; run += tcnt[b*V + v]; }
}

__global__ void k_tok_scatter(const int* __restrict__ tokg, const int* __restrict__ tokl,
                              const int* __restrict__ tog, const int* __restrict__ tol,
                              int* tcur_g, int* tcur_l,
                              int* __restrict__ bucket_g, int* __restrict__ bucket_l){
    __shared__ int lh[VL], lbase[VL], lcur[VL];
    int by = blockIdx.y;
    const int* tok = by ? tokl : tokg;
    const int* toff = by ? tol : tog;
    int* tcur = by ? tcur_l : tcur_g;
    int* bucket = by ? bucket_l : bucket_g;
    int S = by ? SL : SG, V = by ? VL : VG;
    int b = blockIdx.x / CH, c0 = (blockIdx.x % CH)*256;
    int t = threadIdx.x;
    if (t < V){ lh[t] = 0; lcur[t] = 0; }
    __syncthreads();
    int i = c0 + t;
    int v = -1;
    if (i < S){ v = tok[b*S + i]; atomicAdd(&lh[v], 1); }
    __syncthreads();
    if (t < V && lh[t] > 0) lbase[t] = atomicAdd(&tcur[b*V + t], lh[t]);
    __syncthreads();
    if (i < S){
        int p = lbase[v] + atomicAdd(&lcur[v], 1);
        bucket[b*S + toff[b*V + v] + p] = i;
    }
}

// merged transpose: Wr[c*256 + o*8+k] = bf16(W[(o*S+c)*8+k])
__global__ void k_transposeW(const float* __restrict__ W1, const float* __restrict__ W2,
                             bf16* __restrict__ Wr1, bf16* __restrict__ Wr2){
    int c = blockIdx.x, t = threadIdx.x;
    const float* W; bf16* Wr; int S;
    if (c < SG){ W = W1; Wr = Wr1; S = SG; }
    else { c -= SG; W = W2; Wr = Wr2; S = SL; }
    Wr[c*256 + t] = __float2bfloat16(W[((t >> 3)*S + c)*8 + (t & 7)]);
}

__global__ void k_bias0_acc(const float* __restrict__ W, const float* __restrict__ cb1,
                            const float* __restrict__ cb2, float* __restrict__ bias0){
    int o = blockIdx.x, j = threadIdx.x;
    float s = 0.f;
    const float* Wo = W + o*121*128 + j;
    for (int l = 0; l < 121; ++l) s += Wo[l*128];
    unsafeAtomicAdd(&bias0[j], 0.5f * (cb1[o] + cb2[o]) * s);
}

__global__ void k_init_out0(const float* __restrict__ fcxrb, const float* __restrict__ bias0,
                            float* __restrict__ out0){
    int j = threadIdx.x;
    out0[blockIdx.x*128 + j] = fcxrb[j] + bias0[j];
}

extern "C" void kernel_launch(void* const* d_in, const int* in_sizes, int n_in,
                              void* d_out, int out_size, void* d_ws, size_t ws_size,
                              hipStream_t stream)
{
    (void)in_sizes; (void)n_in; (void)out_size; (void)ws_size;

    const float* pro_x  = (const float*)d_in[0];
    const int*   eidx   = (const int*)  d_in[1];
    const float* ew     = (const float*)d_in[2];
    const int*   pbatch = (const int*)  d_in[3];
    const int*   rna_g  = (const int*)  d_in[4];
    const int*   rna_l  = (const int*)  d_in[5];
    const float* emb1   = (const float*)d_in[6];
    const float* emb2   = (const float*)d_in[7];
    const float* convW1 = (const float*)d_in[8];
    const float* convb1 = (const float*)d_in[9];
    const float* convW2 = (const float*)d_in[10];
    const float* convb2 = (const float*)d_in[11];
    const float* fcxrW  = (const float*)d_in[12];
    const float* fcxrb  = (const float*)d_in[13];
    const float* g1W = (const float*)d_in[14];
    const float* g1b = (const float*)d_in[15];
    const float* g2W = (const float*)d_in[16];
    const float* g2b = (const float*)d_in[17];
    const float* g3W = (const float*)d_in[18];
    const float* g3b = (const float*)d_in[19];
    const float* bn1g = (const float*)d_in[20];
    const float* bn1b = (const float*)d_in[21];
    const float* bn2g = (const float*)d_in[22];
    const float* bn2b = (const float*)d_in[23];
    const float* bn3g = (const float*)d_in[24];
    const float* bn3b = (const float*)d_in[25];
    const float* fcg1W = (const float*)d_in[26];
    const float* fcg1b = (const float*)d_in[27];
    const float* fcg2W = (const float*)d_in[28];
    const float* fcg2b = (const float*)d_in[29];

    const int* e_src = eidx;
    const int* e_dst = eidx + NE;

    char* base = (char*)d_ws;
    size_t off = 0;
    auto alloc = [&](size_t bytes)->char*{
        off = (off + 255) & ~(size_t)255;
        char* p = base + off; off += bytes; return p;
    };

    // ---- zero zone (single memset) ----
    double* packed  = (double*)alloc(NN*8);
    int*   tcnt_g  = (int*)  alloc(NB*VG*4);
    int*   tcur_g  = (int*)  alloc(NB*VG*4);
    int*   tcnt_l  = (int*)  alloc(NB*VL*4);
    int*   tcur_l  = (int*)  alloc(NB*VL*4);
    float* bnsum1  = (float*)alloc(2*33*4);
    float* bnsum2  = (float*)alloc(2*66*4);
    float* bnsum3  = (float*)alloc(2*132*4);
    float* poolsum = (float*)alloc(NG*132*4);
    float* bias0   = (float*)alloc(128*4);
    size_t zero_bytes = (off + 255) & ~(size_t)255;

    // ---- persistent buffers ----
    int*    cnt    = (int*)   alloc(NN*4);
    float2* dis12  = (float2*)alloc(NN*8);
    float2* self12 = (float2*)alloc(NN*8);
    int*    offs   = (int*)   alloc(NN*4);
    int*    bsum   = (int*)   alloc(64*4);
    int*    gstart = (int*)   alloc((NG+1)*4);
    float4* epk    = (float4*)alloc((size_t)NE*16);
    float*  bufB   = (float*) alloc((size_t)NN*132*4);   // t (max OF=132)
    bf16*   xbA    = (bf16*)  alloc((size_t)NE*4);       // >= max(slot 6.4MB, NN*40*2)
    bf16*   xbB    = (bf16*)  alloc((size_t)NN*72*2);    // stride-72 features
    float*  Ag     = (float*) alloc((size_t)NB*256*VG*4);   // persistent: read by k_L3
    float*  Al     = (float*) alloc((size_t)NB*256*VL*4);
    bf16*   G1     = (bf16*)  alloc((size_t)32*8*VG*128*2);
    bf16*   G2     = (bf16*)  alloc((size_t)32*8*VL*128*2);

    // slot aliases xbA (consumed by F2 scatter before L1 bn_apply writes xbA)
    int*  slot = (int*)xbA;
    // xb0 (stride-40 cast, 4MB) aliases xbB (first written by L2 bn_apply)
    bf16* xb0  = (bf16*)xbB;

    float* out0 = (float*)d_out;          // xc_rna
    float* out1 = (float*)d_out + 16384;  // xp_out

    // ---- RNA bucketing scratch aliased onto bufB (consumed by F1/F2,
    // which complete before L1 agg_gemm writes bufB) ----
    char* rb = (char*)bufB;
    size_t ro = 0;
    auto ralloc = [&](size_t bytes)->char*{
        ro = (ro + 255) & ~(size_t)255;
        char* p = rb + ro; ro += bytes; return p;
    };
    int* toff_g   = (int*)ralloc(NB*VG*4);
    int* toff_l   = (int*)ralloc(NB*VL*4);
    int* bucket_g = (int*)ralloc((size_t)NB*SG*4);
    int* bucket_l = (int*)ralloc((size_t)NB*SL*4);
    bf16* Wr1     = (bf16*)ralloc((size_t)SG*256*2);
    bf16* Wr2     = (bf16*)ralloc((size_t)SL*256*2);

    hipMemsetAsync(d_ws, 0, zero_bytes, stream);

    // ---- RNA bucketing + weight prep ----
    k_tok_count<<<dim3(NB*CH,2), 256, 0, stream>>>(rna_g, rna_l, tcnt_g, tcnt_l);
    k_tok_off<<<dim3(NB,2), 64, 0, stream>>>(tcnt_g, tcnt_l, toff_g, toff_l);
    k_tok_scatter<<<dim3(NB*CH,2), 256, 0, stream>>>(rna_g, rna_l, toff_g, toff_l,
                                                     tcur_g, tcur_l, bucket_g, bucket_l);
    k_transposeW<<<SG+SL, 256, 0, stream>>>(convW1, convW2, Wr1, Wr2);
    k_bias0_acc<<<32, 128, 0, stream>>>(fcxrW, convb1, convb2, bias0);
    k_init_out0<<<NB, 128, 0, stream>>>(fcxrb, bias0, out0);

    // ---- F1: edge histogram (atomic-latency-bound) co-dispatched with buildA ----
    k_F1<<<EDB + NB*VG + NB*VL, 256, 0, stream>>>(e_dst, ew, packed, slot,
                                                  Wr1, Wr2,
                                                  bucket_g, toff_g, tcnt_g, Ag,
                                                  bucket_l, toff_l, tcnt_l, Al);
    k_prep<<<49, 256, 0, stream>>>(packed, cnt, dis12, self12, pbatch, gstart, bsum);
    k_scan2<<<1, 64, 0, stream>>>(bsum, 49);
    k_scan3<<<49, 256, 0, stream>>>(cnt, bsum, offs);

    // ---- F2: edge scatter co-dispatched with buildG + cast ----
    k_F2<<<EDB + 32*VG + 32*VL + (NN*40+255)/256, 256, 0, stream>>>(
        e_src, e_dst, ew, dis12, offs, slot, epk,
        emb1, emb2, fcxrW, G1, G2, pro_x, xb0);

    // ---- GCN layer 1 (33 -> 33), input stride 40 ----
    k_agg_gemm<5,8,0,0><<<AGB, 256, 0, stream>>>(xb0, epk, offs, cnt, self12,
                                                 g1W, g1b, bufB, 33, 33);
    k_bn_stats<<<256, 64, 0, stream>>>(bufB, bnsum1, 33);
    k_bn_apply<<<(NN*40+255)/256, 256, 0, stream>>>(bufB, bnsum1, bn1g, bn1b,
                                                    xbA, 33, 40, NN*40);

    // ---- GCN layer 2 (33 -> 66), output stride 72 ----
    k_agg_gemm<5,8,0,1><<<AGB, 256, 0, stream>>>(xbA, epk, offs, cnt, self12,
                                                 g2W, g2b, bufB, 33, 66);
    k_bn_stats<<<256, 128, 0, stream>>>(bufB, bnsum2, 66);
    k_bn_apply<<<(NN*72+255)/256, 256, 0, stream>>>(bufB, bnsum2, bn2g, bn2b,
                                                    xbB, 66, 72, NN*72);

    // ---- GCN layer 3 (66 -> 132)  U  RNA-head gemmR ----
    k_L3<<<AGB + 1120, 256, 0, stream>>>(xbB, epk, offs, cnt, self12,
                                         g3W, g3b, bufB, Ag, G1, Al, G2, out0);
    k_bn_stats<<<256, 192, 0, stream>>>(bufB, bnsum3, 132);

    // ---- pool (BN3+relu inline) + fused head ----
    k_poolBN<<<dim3(NG,4), 192, 0, stream>>>(bufB, bnsum3, bn3g, bn3b, gstart, poolsum);
    k_fcgF<<<NG, 1024, 0, stream>>>(poolsum, gstart, fcg1W, fcg1b, fcg2W, fcg2b, out1);
}

// Round 15
// 767.804 us; speedup vs baseline: 1.1238x; 1.0008x over previous
//
#include <hip/hip_runtime.h>
#include <hip/hip_bf16.h>

typedef __hip_bfloat16 bf16;

#define NN 50000      // nodes
#define NE 1600000    // edges (= 6250*256 exactly)
#define NG 128        // graphs
#define NB 128        // rna batch
#define SG 3000       // global seq (channels)
#define SL 2998       // local seq
#define VG 5          // global vocab
#define VL 65         // local vocab
#define EDB 6250      // edge blocks (NE/256)
#define AGB 12500     // agg blocks (NN/4)
#define NA  (NB*VG + NB*VL)   // 1490 buildA blocks
#define NGB (32*VG + 32*VL)   // 2240 buildG blocks
#define CASTB ((NN*40+255)/256)  // 7813

__device__ __forceinline__ float b2f(bf16 x){ return __bfloat162float(x); }
__device__ __forceinline__ float blo(unsigned u){ return __uint_as_float(u << 16); }
__device__ __forceinline__ float bhi(unsigned u){ return __uint_as_float(u & 0xffff0000u); }

// ---------------- F1: buildA FIRST (all co-resident), then edge_deg -------
__device__ void dev_buildA(const bf16* __restrict__ Wr, const int* __restrict__ bucket,
                           const int* __restrict__ toff, const int* __restrict__ tcnt,
                           float* __restrict__ A, int S, int V, int bv){
    int b = bv / V, v = bv - b*V;
    int t = threadIdx.x;            // t = o*8+k
    const int* bk = bucket + b*S + toff[b*V + v];
    int m = tcnt[b*V + v];
    float acc = 0.f;
    int idx = 0;
    for (; idx + 4 <= m; idx += 4){
        int c0 = bk[idx], c1 = bk[idx+1], c2 = bk[idx+2], c3 = bk[idx+3];
        acc += b2f(Wr[c0*256 + t]);
        acc += b2f(Wr[c1*256 + t]);
        acc += b2f(Wr[c2*256 + t]);
        acc += b2f(Wr[c3*256 + t]);
    }
    for (; idx < m; ++idx) acc += b2f(Wr[bk[idx]*256 + t]);
    A[b*(256*V) + t*V + v] = acc;
}

// blocks [0,NA): buildA (1490 < ~2048 machine capacity -> all resident);
// blocks [NA, NA+EDB): edge histogram. Simple prefix split, reordered.
__global__ void k_F1(const int* __restrict__ dst, const float* __restrict__ ew,
                     double* __restrict__ packed, int* __restrict__ slot,
                     const bf16* __restrict__ Wr1, const bf16* __restrict__ Wr2,
                     const int* __restrict__ bucket_g, const int* __restrict__ toff_g,
                     const int* __restrict__ tcnt_g, float* __restrict__ Ag,
                     const int* __restrict__ bucket_l, const int* __restrict__ toff_l,
                     const int* __restrict__ tcnt_l, float* __restrict__ Al){
    int bx = blockIdx.x;
    if (bx < NA){
        if (bx < NB*VG) dev_buildA(Wr1, bucket_g, toff_g, tcnt_g, Ag, SG, VG, bx);
        else dev_buildA(Wr2, bucket_l, toff_l, tcnt_l, Al, SL, VL, bx - NB*VG);
        return;
    }
    int e = (bx - NA)*256 + threadIdx.x;
    double old = unsafeAtomicAdd(&packed[dst[e]], 1048576.0 + (double)ew[e]);
    slot[e] = (int)(old * (1.0/1048576.0));
}

// fused node_dis + gbounds + scan1: grid 49 x 256, 4 nodes/thread
__global__ void k_prep(const double* __restrict__ packed, int* __restrict__ cnt,
                       float2* __restrict__ dis12, float2* __restrict__ self12,
                       const int* __restrict__ batch, int* __restrict__ gstart,
                       int* __restrict__ bsum){
    __shared__ int sd[256];
    int t = threadIdx.x;
    int base = blockIdx.x*1024;
    int s = 0;
    #pragma unroll
    for (int j = 0; j < 4; ++j){
        int i = base + t*4 + j;
        if (i < NN){
            double p = packed[i];
            int c = (int)(p * (1.0/1048576.0));
            float w = (float)(p - (double)c * 1048576.0);
            cnt[i] = c; s += c;
            float r1 = rsqrtf(w + 1.0f);
            float r2 = rsqrtf((float)c + 1.0f);
            dis12[i] = make_float2(r1, r2);
            self12[i] = make_float2(r1*r1, r2*r2);
            int pb = batch[i];
            int prev = (i == 0) ? -1 : batch[i-1];
            for (int g = prev + 1; g <= pb; ++g) gstart[g] = i;
            if (i == NN - 1){
                for (int g = pb + 1; g <= NG; ++g) gstart[g] = NN;
            }
        }
    }
    sd[t] = s; __syncthreads();
    for (int d = 128; d > 0; d >>= 1){
        if (t < d) sd[t] += sd[t+d];
        __syncthreads();
    }
    if (t == 0) bsum[blockIdx.x] = sd[0];
}

__global__ void k_scan2(int* bsum, int nb){
    if (threadIdx.x == 0 && blockIdx.x == 0){
        int run = 0;
        for (int i = 0; i < nb; ++i){ int v = bsum[i]; bsum[i] = run; run += v; }
    }
}

__global__ void k_scan3(const int* __restrict__ cnt, const int* __restrict__ bsum,
                        int* __restrict__ offs){
    __shared__ int sd[256];
    int t = threadIdx.x;
    int base = blockIdx.x*1024;
    int loc[4]; int s = 0;
    #pragma unroll
    for (int j = 0; j < 4; ++j){
        int idx = base + t*4 + j;
        loc[j] = (idx < NN) ? cnt[idx] : 0;
        s += loc[j];
    }
    sd[t] = s; __syncthreads();
    for (int d = 1; d < 256; d <<= 1){
        int v = (t >= d) ? sd[t-d] : 0;
        __syncthreads();
        sd[t] += v;
        __syncthreads();
    }
    int run = bsum[blockIdx.x] + (sd[t] - s);
    #pragma unroll
    for (int j = 0; j < 4; ++j){
        int idx = base + t*4 + j;
        if (idx < NN) offs[idx] = run;
        run += loc[j];
    }
}

// ---------------- F2: buildG FIRST, then scatter, then cast ----------------
__device__ void dev_buildG(float (*rows)[128], const float* __restrict__ emb,
                           const float* __restrict__ W, bf16* __restrict__ G,
                           int V, int q){
    int o = q / V, mt = q - o*V;      // M = 8V, one block = 8 consecutive m
    int t = threadIdx.x;              // 256
    int j = t & 127, half = t >> 7;
    int kk[4];
    #pragma unroll
    for (int qq = 0; qq < 4; ++qq){
        int mm = half*4 + qq;
        int m = mt*8 + mm;
        int k = m / V, v = m - k*V;
        kk[qq] = k;
        rows[mm][j] = emb[v*128 + j];
    }
    __syncthreads();
    float a0=0.f, a1=0.f, a2=0.f, a3=0.f;
    const float* Wo = W + o*121*128 + j;
    for (int l = 0; l < 121; ++l){
        float w = Wo[l*128];
        a0 += rows[half*4+0][l + kk[0]] * w;
        a1 += rows[half*4+1][l + kk[1]] * w;
        a2 += rows[half*4+2][l + kk[2]] * w;
        a3 += rows[half*4+3][l + kk[3]] * w;
    }
    int M = 8*V;
    int base = (o*M + mt*8 + half*4)*128 + j;
    G[base      ] = __float2bfloat16(a0);
    G[base + 128] = __float2bfloat16(a1);
    G[base + 256] = __float2bfloat16(a2);
    G[base + 384] = __float2bfloat16(a3);
}

// blocks [0,NGB): buildG; [NGB, NGB+EDB): scatter; rest: cast.
// epk record: (srcByteOff stride40, n1, n2, srcByteOff stride72)
__global__ void k_F2(const int* __restrict__ src, const int* __restrict__ dst,
                     const float* __restrict__ ew, const float2* __restrict__ dis12,
                     const int* __restrict__ offs, const int* __restrict__ slot,
                     float4* __restrict__ epk,
                     const float* __restrict__ emb1, const float* __restrict__ emb2,
                     const float* __restrict__ fcxrW, bf16* __restrict__ G1,
                     bf16* __restrict__ G2,
                     const float* __restrict__ pro_x, bf16* __restrict__ xb0){
    __shared__ float rows[8][128];
    int bx = blockIdx.x;
    if (bx < 32*VG){ dev_buildG(rows, emb1, fcxrW, G1, VG, bx); return; }
    if (bx < NGB){ dev_buildG(rows, emb2, fcxrW, G2, VL, bx - 32*VG); return; }
    bx -= NGB;
    if (bx < EDB){
        int e = bx*256 + threadIdx.x;
        int s = src[e], d = dst[e];
        int pos = offs[d] + slot[e];
        float2 a = dis12[s], b = dis12[d];
        float4 v;
        v.x = __int_as_float(s*80);    // byte offset, stride-40 bf16
        v.y = a.x * ew[e] * b.x;       // norm layer 1
        v.z = a.y * b.y;               // norm layers 2/3
        v.w = __int_as_float(s*144);   // byte offset, stride-72 bf16
        epk[pos] = v;
        return;
    }
    bx -= EDB;
    int i = bx*256 + threadIdx.x;     // cast pro_x -> padded bf16 [NN,40]
    if (i >= NN*40) return;
    int n = i / 40, f = i - n*40;
    xb0[i] = __float2bfloat16(f < 33 ? pro_x[n*33 + f] : 0.f);
}

// ---------------- fused aggregate + GEMM (uint4 rows) ----------------
// QV = uint4s per padded row; GRP edge-groups per wave; OFF_W/N_Z pick epk lanes.
// Epilogue: thread j computes all 4 nodes' output j (1 W-load per 4 FMA).
template<int QV, int GRP, int OFF_W, int N_Z>
__device__ void dev_agg(float* sAgg /* [4][QV*8] */,
                        const bf16* __restrict__ xb, const float4* __restrict__ epk,
                        const int* __restrict__ offs, const int* __restrict__ cnt,
                        const float2* __restrict__ self12,
                        const float* __restrict__ W, const float* __restrict__ bias,
                        float* __restrict__ tout, int F, int OF, int bx){
    const int LPG = 64 / GRP;
    int wave = threadIdx.x >> 6;
    int node = bx*4 + wave;
    int lane = threadIdx.x & 63;
    int grp  = lane / LPG;
    int gl   = lane % LPG;
    bool act = gl < QV;
    const char* xc = (const char*)xb;
    float a0=0,a1=0,a2=0,a3=0,a4=0,a5=0,a6=0,a7=0;
    int b = offs[node], e = b + cnt[node];
    if (act){
        int fo = gl << 4;   // lane byte offset within row
        if (grp == 0){
            float2 sw2 = self12[node];
            float sw = N_Z ? sw2.y : sw2.x;
            uint4 u = *(const uint4*)(xc + node*(QV*16) + fo);
            a0 = sw*blo(u.x); a1 = sw*bhi(u.x); a2 = sw*blo(u.y); a3 = sw*bhi(u.y);
            a4 = sw*blo(u.z); a5 = sw*bhi(u.z); a6 = sw*blo(u.w); a7 = sw*bhi(u.w);
        }
        int p = b + grp;
        for (; p + 3*GRP < e; p += 4*GRP){
            float4 e0 = epk[p];
            float4 e1 = epk[p +   GRP];
            float4 e2 = epk[p + 2*GRP];
            float4 e3 = epk[p + 3*GRP];
            int o0 = __float_as_int(OFF_W ? e0.w : e0.x); float n0 = N_Z ? e0.z : e0.y;
            int o1 = __float_as_int(OFF_W ? e1.w : e1.x); float n1 = N_Z ? e1.z : e1.y;
            int o2 = __float_as_int(OFF_W ? e2.w : e2.x); float n2 = N_Z ? e2.z : e2.y;
            int o3 = __float_as_int(OFF_W ? e3.w : e3.x); float n3 = N_Z ? e3.z : e3.y;
            uint4 u0 = *(const uint4*)(xc + o0 + fo);
            uint4 u1 = *(const uint4*)(xc + o1 + fo);
            uint4 u2 = *(const uint4*)(xc + o2 + fo);
            uint4 u3 = *(const uint4*)(xc + o3 + fo);
            a0 += n0*blo(u0.x); a1 += n0*bhi(u0.x); a2 += n0*blo(u0.y); a3 += n0*bhi(u0.y);
            a4 += n0*blo(u0.z); a5 += n0*bhi(u0.z); a6 += n0*blo(u0.w); a7 += n0*bhi(u0.w);
            a0 += n1*blo(u1.x); a1 += n1*bhi(u1.x); a2 += n1*blo(u1.y); a3 += n1*bhi(u1.y);
            a4 += n1*blo(u1.z); a5 += n1*bhi(u1.z); a6 += n1*blo(u1.w); a7 += n1*bhi(u1.w);
            a0 += n2*blo(u2.x); a1 += n2*bhi(u2.x); a2 += n2*blo(u2.y); a3 += n2*bhi(u2.y);
            a4 += n2*blo(u2.z); a5 += n2*bhi(u2.z); a6 += n2*blo(u2.w); a7 += n2*bhi(u2.w);
            a0 += n3*blo(u3.x); a1 += n3*bhi(u3.x); a2 += n3*blo(u3.y); a3 += n3*bhi(u3.y);
            a4 += n3*blo(u3.z); a5 += n3*bhi(u3.z); a6 += n3*blo(u3.w); a7 += n3*bhi(u3.w);
        }
        for (; p < e; p += GRP){
            float4 e0 = epk[p];
            int o0 = __float_as_int(OFF_W ? e0.w : e0.x); float n0 = N_Z ? e0.z : e0.y;
            uint4 u0 = *(const uint4*)(xc + o0 + fo);
            a0 += n0*blo(u0.x); a1 += n0*bhi(u0.x); a2 += n0*blo(u0.y); a3 += n0*bhi(u0.y);
            a4 += n0*blo(u0.z); a5 += n0*bhi(u0.z); a6 += n0*blo(u0.w); a7 += n0*bhi(u0.w);
        }
    }
    #pragma unroll
    for (int m = LPG; m < 64; m <<= 1){
        a0 += __shfl_xor(a0, m); a1 += __shfl_xor(a1, m);
        a2 += __shfl_xor(a2, m); a3 += __shfl_xor(a3, m);
        a4 += __shfl_xor(a4, m); a5 += __shfl_xor(a5, m);
        a6 += __shfl_xor(a6, m); a7 += __shfl_xor(a7, m);
    }
    if (act && grp == 0){
        float4* dst = (float4*)&sAgg[wave*(QV*8) + gl*8];
        dst[0] = make_float4(a0, a1, a2, a3);
        dst[1] = make_float4(a4, a5, a6, a7);
    }
    __syncthreads();
    int i0 = bx*4;
    int j = threadIdx.x;
    if (j < OF){
        float c0 = bias[j], c1 = c0, c2 = c0, c3 = c0;
        const float* Wj = W + j;
        const float* s0 = sAgg;
        const float* s1 = sAgg + QV*8;
        const float* s2 = sAgg + 2*QV*8;
        const float* s3 = sAgg + 3*QV*8;
        #pragma unroll 4
        for (int f = 0; f < F; ++f){
            float w = Wj[f*OF];
            c0 += s0[f]*w; c1 += s1[f]*w; c2 += s2[f]*w; c3 += s3[f]*w;
        }
        tout[(size_t)(i0+0)*OF + j] = c0;
        tout[(size_t)(i0+1)*OF + j] = c1;
        tout[(size_t)(i0+2)*OF + j] = c2;
        tout[(size_t)(i0+3)*OF + j] = c3;
    }
}

template<int QV, int GRP, int OFF_W, int N_Z>
__global__ void k_agg_gemm(const bf16* __restrict__ xb, const float4* __restrict__ epk,
                           const int* __restrict__ offs, const int* __restrict__ cnt,
                           const float2* __restrict__ self12,
                           const float* __restrict__ W, const float* __restrict__ bias,
                           float* __restrict__ tout, int F, int OF){
    __shared__ float sAgg[4*QV*8];
    dev_agg<QV,GRP,OFF_W,N_Z>(sAgg, xb, epk, offs, cnt, self12, W, bias,
                              tout, F, OF, blockIdx.x);
}

// gemmR for 256 threads: 8 b-rows x 256-K slice, atomic epilogue
__device__ void dev_gemmR(float* xs /* [8][256] */, int bq,
                          const float* __restrict__ Ag, const bf16* __restrict__ G1,
                          const float* __restrict__ Al, const bf16* __restrict__ G2,
                          float* __restrict__ out0){
    int kpart = bq >> 4;       // 0..69
    int bgrp  = bq & 15;
    const float* X; const bf16* G; int K, k0;
    if (kpart < 5){ X = Ag; G = G1; K = 1280;  k0 = kpart*256; }
    else          { X = Al; G = G2; K = 16640; k0 = (kpart-5)*256; }
    int b0 = bgrp*8;
    int t = threadIdx.x;
    #pragma unroll
    for (int i = 0; i < 8; ++i)
        xs[i*256 + t] = X[(b0+i)*K + k0 + t];
    __syncthreads();
    int rq = t >> 7, j = t & 127;
    const float* x0 = xs + (rq*4)*256;
    float a0=0,a1=0,a2=0,a3=0;
    const bf16* Gp = G + (size_t)k0*128 + j;
    for (int kk = 0; kk < 256; ++kk){
        float g = b2f(Gp[kk*128]);
        a0 += x0[kk]*g; a1 += x0[256+kk]*g; a2 += x0[512+kk]*g; a3 += x0[768+kk]*g;
    }
    unsafeAtomicAdd(&out0[(b0+rq*4+0)*128 + j], 0.5f*a0);
    unsafeAtomicAdd(&out0[(b0+rq*4+1)*128 + j], 0.5f*a1);
    unsafeAtomicAdd(&out0[(b0+rq*4+2)*128 + j], 0.5f*a2);
    unsafeAtomicAdd(&out0[(b0+rq*4+3)*128 + j], 0.5f*a3);
}

// L3 aggregate+gemm  U  gemmR (RNA head backfills L3's latency stalls)
__global__ void k_L3(const bf16* __restrict__ xb, const float4* __restrict__ epk,
                     const int* __restrict__ offs, const int* __restrict__ cnt,
                     const float2* __restrict__ self12,
                     const float* __restrict__ W, const float* __restrict__ bias,
                     float* __restrict__ tout,
                     const float* __restrict__ Ag, const bf16* __restrict__ G1,
                     const float* __restrict__ Al, const bf16* __restrict__ G2,
                     float* __restrict__ out0){
    __shared__ float smem[8*256];
    int bx = blockIdx.x;
    if (bx < AGB){
        dev_agg<9,4,1,1>(smem, xb, epk, offs, cnt, self12, W, bias, tout, 66, 132, bx);
    } else {
        dev_gemmR(smem, bx - AGB, Ag, G1, Al, G2, out0);
    }
}

__global__ void k_bn_stats(const float* __restrict__ t, float* __restrict__ sums, int OF){
    int f = threadIdx.x;
    if (f >= OF) return;
    float s = 0.f, ss = 0.f;
    for (int i = blockIdx.x; i < NN; i += gridDim.x){
        float v = t[(size_t)i*OF + f];
        s += v; ss += v*v;
    }
    unsafeAtomicAdd(&sums[f], s);
    unsafeAtomicAdd(&sums[OF + f], ss);
}

// fused finalize+apply, flattened; padded bf16 out (stride OS)
__global__ void k_bn_apply(const float* __restrict__ t, const float* __restrict__ sums,
                           const float* __restrict__ g, const float* __restrict__ b,
                           bf16* __restrict__ xo, int OF, int OS, int total){
    int id = blockIdx.x*256 + threadIdx.x;
    if (id >= total) return;
    int i = id / OS, f = id - i*OS;
    float v = 0.f;
    if (f < OF){
        float m  = sums[f] * (1.0f/(float)NN);
        float vr = sums[OF + f] * (1.0f/(float)NN) - m*m;
        float sc = g[f] * rsqrtf(vr + 1e-5f);
        float sh = b[f] - m*sc;
        v = t[(size_t)i*OF + f] * sc + sh;
        v = v > 0.f ? v : 0.f;
    }
    xo[id] = __float2bfloat16(v);
}

// pool with BN3+relu inline, reading fp32 t; grid (NG,4) strips
__global__ void k_poolBN(const float* __restrict__ t, const float* __restrict__ sums,
                         const float* __restrict__ g, const float* __restrict__ b,
                         const int* __restrict__ gstart, float* __restrict__ poolsum){
    int gr = blockIdx.x, strip = blockIdx.y, f = threadIdx.x;
    if (f >= 132) return;
    float m  = sums[f] * (1.0f/(float)NN);
    float vr = sums[132 + f] * (1.0f/(float)NN) - m*m;
    float sc = g[f] * rsqrtf(vr + 1e-5f);
    float sh = b[f] - m*sc;
    int i0 = gstart[gr], i1 = gstart[gr+1];
    float s = 0.f;
    for (int i = i0 + strip; i < i1; i += 4){
        float v = t[(size_t)i*132 + f] * sc + sh;
        s += v > 0.f ? v : 0.f;
    }
    unsafeAtomicAdd(&poolsum[gr*132 + f], s);
}

// fused fcg1+fcg2: block g computes h[g,:] in LDS then the 128-out GEMV
__global__ void k_fcgF(const float* __restrict__ poolsum, const int* __restrict__ gstart,
                       const float* __restrict__ W1, const float* __restrict__ b1,
                       const float* __restrict__ W2, const float* __restrict__ b2,
                       float* __restrict__ out){
    __shared__ float pr[132];
    __shared__ float hr[1024];
    __shared__ float part[8][128];
    int g = blockIdx.x, t = threadIdx.x;   // 1024
    if (t < 132){
        float inv = 1.0f / fmaxf((float)(gstart[g+1] - gstart[g]), 1.0f);
        pr[t] = poolsum[g*132 + t] * inv;
    }
    __syncthreads();
    float acc = b1[t];
    #pragma unroll 4
    for (int f = 0; f < 132; ++f) acc += pr[f] * W1[f*1024 + t];
    hr[t] = acc > 0.f ? acc : 0.f;
    __syncthreads();
    int ks = t >> 7, j = t & 127;
    const float* Wp = W2 + (ks*128)*128 + j;
    const float* hp = hr + ks*128;
    float a = 0.f;
    #pragma unroll 8
    for (int kk = 0; kk < 128; ++kk) a += hp[kk] * Wp[(size_t)kk*128];
    part[ks][j] = a;
    __syncthreads();
    if (t < 128){
        float s = b2[t];
        #pragma unroll
        for (int r = 0; r < 8; ++r) s += part[r][t];
        out[g*128 + t] = s;
    }
}

// ---------------- RNA bucketing (merged g/l via blockIdx.y) ----------------
#define CH 12   // ceil(S/256) for both S=3000 and 2998

__global__ void k_tok_count(const int* __restrict__ tokg, const int* __restrict__ tokl,
                            int* tcg, int* tcl){
    __shared__ int lh[VL];
    int by = blockIdx.y;
    const int* tok = by ? tokl : tokg;
    int S = by ? SL : SG, V = by ? VL : VG;
    int* tcnt = by ? tcl : tcg;
    int b = blockIdx.x / CH, c0 = (blockIdx.x % CH)*256;
    int t = threadIdx.x;
    if (t < V) lh[t] = 0;
    __syncthreads();
    int i = c0 + t;
    if (i < S) atomicAdd(&lh[tok[b*S + i]], 1);
    __syncthreads();
    if (t < V && lh[t] > 0) atomicAdd(&tcnt[b*V + t], lh[t]);
}

__global__ void k_tok_off(const int* __restrict__ tcg, const int* __restrict__ tcl,
                          int* tog, int* tol){
    int by = blockIdx.y;
    const int* tcnt = by ? tcl : tcg;
    int* toff = by ? tol : tog;
    int V = by ? VL : VG;
    int b = blockIdx.x;
    if (threadIdx.x != 0) return;
    int run = 0;
    for (int v = 0; v < V; ++v){ toff[b*V + v] = run; run += tcnt[b*V + v]; }
}

__global__ void k_tok_scatter(const int* __restrict__ tokg, const int* __restrict__ tokl,
                              const int* __restrict__ tog, const int* __restrict__ tol,
                              int* tcur_g, int* tcur_l,
                              int* __restrict__ bucket_g, int* __restrict__ bucket_l){
    __shared__ int lh[VL], lbase[VL], lcur[VL];
    int by = blockIdx.y;
    const int* tok = by ? tokl : tokg;
    const int* toff = by ? tol : tog;
    int* tcur = by ? tcur_l : tcur_g;
    int* bucket = by ? bucket_l : bucket_g;
    int S = by ? SL : SG, V = by ? VL : VG;
    int b = blockIdx.x / CH, c0 = (blockIdx.x % CH)*256;
    int t = threadIdx.x;
    if (t < V){ lh[t] = 0; lcur[t] = 0; }
    __syncthreads();
    int i = c0 + t;
    int v = -1;
    if (i < S){ v = tok[b*S + i]; atomicAdd(&lh[v], 1); }
    __syncthreads();
    if (t < V && lh[t] > 0) lbase[t] = atomicAdd(&tcur[b*V + t], lh[t]);
    __syncthreads();
    if (i < S){
        int p = lbase[v] + atomicAdd(&lcur[v], 1);
        bucket[b*S + toff[b*V + v] + p] = i;
    }
}

// merged transpose: Wr[c*256 + o*8+k] = bf16(W[(o*S+c)*8+k])
__global__ void k_transposeW(const float* __restrict__ W1, const float* __restrict__ W2,
                             bf16* __restrict__ Wr1, bf16* __restrict__ Wr2){
    int c = blockIdx.x, t = threadIdx.x;
    const float* W; bf16* Wr; int S;
    if (c < SG){ W = W1; Wr = Wr1; S = SG; }
    else { c -= SG; W = W2; Wr = Wr2; S = SL; }
    Wr[c*256 + t] = __float2bfloat16(W[((t >> 3)*S + c)*8 + (t & 7)]);
}

__global__ void k_bias0_acc(const float* __restrict__ W, const float* __restrict__ cb1,
                            const float* __restrict__ cb2, float* __restrict__ bias0){
    int o = blockIdx.x, j = threadIdx.x;
    float s = 0.f;
    const float* Wo = W + o*121*128 + j;
    for (int l = 0; l < 121; ++l) s += Wo[l*128];
    unsafeAtomicAdd(&bias0[j], 0.5f * (cb1[o] + cb2[o]) * s);
}

__global__ void k_init_out0(const float* __restrict__ fcxrb, const float* __restrict__ bias0,
                            float* __restrict__ out0){
    int j = threadIdx.x;
    out0[blockIdx.x*128 + j] = fcxrb[j] + bias0[j];
}

extern "C" void kernel_launch(void* const* d_in, const int* in_sizes, int n_in,
                              void* d_out, int out_size, void* d_ws, size_t ws_size,
                              hipStream_t stream)
{
    (void)in_sizes; (void)n_in; (void)out_size; (void)ws_size;

    const float* pro_x  = (const float*)d_in[0];
    const int*   eidx   = (const int*)  d_in[1];
    const float* ew     = (const float*)d_in[2];
    const int*   pbatch = (const int*)  d_in[3];
    const int*   rna_g  = (const int*)  d_in[4];
    const int*   rna_l  = (const int*)  d_in[5];
    const float* emb1   = (const float*)d_in[6];
    const float* emb2   = (const float*)d_in[7];
    const float* convW1 = (const float*)d_in[8];
    const float* convb1 = (const float*)d_in[9];
    const float* convW2 = (const float*)d_in[10];
    const float* convb2 = (const float*)d_in[11];
    const float* fcxrW  = (const float*)d_in[12];
    const float* fcxrb  = (const float*)d_in[13];
    const float* g1W = (const float*)d_in[14];
    const float* g1b = (const float*)d_in[15];
    const float* g2W = (const float*)d_in[16];
    const float* g2b = (const float*)d_in[17];
    const float* g3W = (const float*)d_in[18];
    const float* g3b = (const float*)d_in[19];
    const float* bn1g = (const float*)d_in[20];
    const float* bn1b = (const float*)d_in[21];
    const float* bn2g = (const float*)d_in[22];
    const float* bn2b = (const float*)d_in[23];
    const float* bn3g = (const float*)d_in[24];
    const float* bn3b = (const float*)d_in[25];
    const float* fcg1W = (const float*)d_in[26];
    const float* fcg1b = (const float*)d_in[27];
    const float* fcg2W = (const float*)d_in[28];
    const float* fcg2b = (const float*)d_in[29];

    const int* e_src = eidx;
    const int* e_dst = eidx + NE;

    char* base = (char*)d_ws;
    size_t off = 0;
    auto alloc = [&](size_t bytes)->char*{
        off = (off + 255) & ~(size_t)255;
        char* p = base + off; off += bytes; return p;
    };

    // ---- zero zone (single memset) ----
    double* packed  = (double*)alloc(NN*8);
    int*   tcnt_g  = (int*)  alloc(NB*VG*4);
    int*   tcur_g  = (int*)  alloc(NB*VG*4);
    int*   tcnt_l  = (int*)  alloc(NB*VL*4);
    int*   tcur_l  = (int*)  alloc(NB*VL*4);
    float* bnsum1  = (float*)alloc(2*33*4);
    float* bnsum2  = (float*)alloc(2*66*4);
    float* bnsum3  = (float*)alloc(2*132*4);
    float* poolsum = (float*)alloc(NG*132*4);
    float* bias0   = (float*)alloc(128*4);
    size_t zero_bytes = (off + 255) & ~(size_t)255;

    // ---- persistent buffers ----
    int*    cnt    = (int*)   alloc(NN*4);
    float2* dis12  = (float2*)alloc(NN*8);
    float2* self12 = (float2*)alloc(NN*8);
    int*    offs   = (int*)   alloc(NN*4);
    int*    bsum   = (int*)   alloc(64*4);
    int*    gstart = (int*)   alloc((NG+1)*4);
    float4* epk    = (float4*)alloc((size_t)NE*16);
    float*  bufB   = (float*) alloc((size_t)NN*132*4);   // t (max OF=132)
    bf16*   xbA    = (bf16*)  alloc((size_t)NE*4);       // >= max(slot 6.4MB, NN*40*2)
    bf16*   xbB    = (bf16*)  alloc((size_t)NN*72*2);    // stride-72 features
    float*  Ag     = (float*) alloc((size_t)NB*256*VG*4);   // persistent: read by k_L3
    float*  Al     = (float*) alloc((size_t)NB*256*VL*4);
    bf16*   G1     = (bf16*)  alloc((size_t)32*8*VG*128*2);
    bf16*   G2     = (bf16*)  alloc((size_t)32*8*VL*128*2);

    // slot aliases xbA (consumed by F2 scatter before L1 bn_apply writes xbA)
    int*  slot = (int*)xbA;
    // xb0 (stride-40 cast, 4MB) aliases xbB (first written by L2 bn_apply)
    bf16* xb0  = (bf16*)xbB;

    float* out0 = (float*)d_out;          // xc_rna
    float* out1 = (float*)d_out + 16384;  // xp_out

    // ---- RNA bucketing scratch aliased onto bufB (consumed by F1/F2,
    // which complete before L1 agg_gemm writes bufB) ----
    char* rb = (char*)bufB;
    size_t ro = 0;
    auto ralloc = [&](size_t bytes)->char*{
        ro = (ro + 255) & ~(size_t)255;
        char* p = rb + ro; ro += bytes; return p;
    };
    int* toff_g   = (int*)ralloc(NB*VG*4);
    int* toff_l   = (int*)ralloc(NB*VL*4);
    int* bucket_g = (int*)ralloc((size_t)NB*SG*4);
    int* bucket_l = (int*)ralloc((size_t)NB*SL*4);
    bf16* Wr1     = (bf16*)ralloc((size_t)SG*256*2);
    bf16* Wr2     = (bf16*)ralloc((size_t)SL*256*2);

    hipMemsetAsync(d_ws, 0, zero_bytes, stream);

    // ---- RNA bucketing + weight prep ----
    k_tok_count<<<dim3(NB*CH,2), 256, 0, stream>>>(rna_g, rna_l, tcnt_g, tcnt_l);
    k_tok_off<<<dim3(NB,2), 64, 0, stream>>>(tcnt_g, tcnt_l, toff_g, toff_l);
    k_tok_scatter<<<dim3(NB*CH,2), 256, 0, stream>>>(rna_g, rna_l, toff_g, toff_l,
                                                     tcur_g, tcur_l, bucket_g, bucket_l);
    k_transposeW<<<SG+SL, 256, 0, stream>>>(convW1, convW2, Wr1, Wr2);
    k_bias0_acc<<<32, 128, 0, stream>>>(fcxrW, convb1, convb2, bias0);
    k_init_out0<<<NB, 128, 0, stream>>>(fcxrb, bias0, out0);

    // ---- F1: buildA first (all co-resident), edge histogram streams after ----
    k_F1<<<NA + EDB, 256, 0, stream>>>(e_dst, ew, packed, slot,
                                       Wr1, Wr2,
                                       bucket_g, toff_g, tcnt_g, Ag,
                                       bucket_l, toff_l, tcnt_l, Al);
    k_prep<<<49, 256, 0, stream>>>(packed, cnt, dis12, self12, pbatch, gstart, bsum);
    k_scan2<<<1, 64, 0, stream>>>(bsum, 49);
    k_scan3<<<49, 256, 0, stream>>>(cnt, bsum, offs);

    // ---- F2: buildG first, then edge scatter, then cast ----
    k_F2<<<NGB + EDB + CASTB, 256, 0, stream>>>(
        e_src, e_dst, ew, dis12, offs, slot, epk,
        emb1, emb2, fcxrW, G1, G2, pro_x, xb0);

    // ---- GCN layer 1 (33 -> 33), input stride 40 ----
    k_agg_gemm<5,8,0,0><<<AGB, 256, 0, stream>>>(xb0, epk, offs, cnt, self12,
                                                 g1W, g1b, bufB, 33, 33);
    k_bn_stats<<<256, 64, 0, stream>>>(bufB, bnsum1, 33);
    k_bn_apply<<<(NN*40+255)/256, 256, 0, stream>>>(bufB, bnsum1, bn1g, bn1b,
                                                    xbA, 33, 40, NN*40);

    // ---- GCN layer 2 (33 -> 66), output stride 72 ----
    k_agg_gemm<5,8,0,1><<<AGB, 256, 0, stream>>>(xbA, epk, offs, cnt, self12,
                                                 g2W, g2b, bufB, 33, 66);
    k_bn_stats<<<256, 128, 0, stream>>>(bufB, bnsum2, 66);
    k_bn_apply<<<(NN*72+255)/256, 256, 0, stream>>>(bufB, bnsum2, bn2g, bn2b,
                                                    xbB, 66, 72, NN*72);

    // ---- GCN layer 3 (66 -> 132)  U  RNA-head gemmR ----
    k_L3<<<AGB + 1120, 256, 0, stream>>>(xbB, epk, offs, cnt, self12,
                                         g3W, g3b, bufB, Ag, G1, Al, G2, out0);
    k_bn_stats<<<256, 192, 0, stream>>>(bufB, bnsum3, 132);

    // ---- pool (BN3+relu inline) + fused head ----
    k_poolBN<<<dim3(NG,4), 192, 0, stream>>>(bufB, bnsum3, bn3g, bn3b, gstart, poolsum);
    k_fcgF<<<NG, 1024, 0, stream>>>(poolsum, gstart, fcg1W, fcg1b, fcg2W, fcg2b, out1);
}

// Round 16
// 738.777 us; speedup vs baseline: 1.1680x; 1.0393x over previous
//
#include <hip/hip_runtime.h>
#include <hip/hip_bf16.h>

typedef __hip_bfloat16 bf16;

#define NN 50000      // nodes
#define NE 1600000    // edges (= 6250*256 exactly)
#define NG 128        // graphs
#define NB 128        // rna batch
#define SG 3000       // global seq (channels)
#define SL 2998       // local seq
#define VG 5          // global vocab
#define VL 65         // local vocab
#define EDB 6250      // edge blocks (NE/256)
#define AGB 12500     // agg blocks (NN/4)
#define NA  (NB*VG + NB*VL)   // 1490 buildA blocks
#define NGB (32*VG + 32*VL)   // 2240 buildG blocks
#define CASTB ((NN*40+255)/256)  // 7813

__device__ __forceinline__ float b2f(bf16 x){ return __bfloat162float(x); }
__device__ __forceinline__ float blo(unsigned u){ return __uint_as_float(u << 16); }
__device__ __forceinline__ float bhi(unsigned u){ return __uint_as_float(u & 0xffff0000u); }

// ---------------- k_front: bucketing U transposeW U bias0_acc --------------
// blocks [0,2NB): per-(b,branch) LDS bucketing (count+prefix+scatter);
// [2NB, 2NB+SG+SL): conv-W transpose to fp32; last 32: bias0 partials.
__global__ void k_front(const int* __restrict__ rna_g, const int* __restrict__ rna_l,
                        int* __restrict__ tcnt_g, int* __restrict__ toff_g,
                        int* __restrict__ bucket_g,
                        int* __restrict__ tcnt_l, int* __restrict__ toff_l,
                        int* __restrict__ bucket_l,
                        const float* __restrict__ convW1, const float* __restrict__ convW2,
                        float* __restrict__ Wr1, float* __restrict__ Wr2,
                        const float* __restrict__ fcxrW, const float* __restrict__ cb1,
                        const float* __restrict__ cb2, float* __restrict__ bias0){
    int bx = blockIdx.x;
    int t = threadIdx.x;
    if (bx < 2*NB){
        __shared__ int hist[VL], pre[VL], cur[VL];
        int br = bx & 1, b = bx >> 1;
        const int* tok = br ? rna_l : rna_g;
        int S = br ? SL : SG, V = br ? VL : VG;
        int* tcnt = br ? tcnt_l : tcnt_g;
        int* toff = br ? toff_l : toff_g;
        int* bucket = br ? bucket_l : bucket_g;
        if (t < V) hist[t] = 0;
        __syncthreads();
        for (int i = t; i < S; i += 256) atomicAdd(&hist[tok[b*S + i]], 1);
        __syncthreads();
        if (t == 0){
            int run = 0;
            for (int v = 0; v < V; ++v){ pre[v] = run; run += hist[v]; }
        }
        __syncthreads();
        if (t < V){
            tcnt[b*V + t] = hist[t];
            toff[b*V + t] = pre[t];
            cur[t] = pre[t];
        }
        __syncthreads();
        for (int i = t; i < S; i += 256){
            int v = tok[b*S + i];
            int p = atomicAdd(&cur[v], 1);
            bucket[b*S + p] = i;
        }
        return;
    }
    bx -= 2*NB;
    if (bx < SG + SL){
        const float* W; float* Wr; int S, c = bx;
        if (c < SG){ W = convW1; Wr = Wr1; S = SG; }
        else { c -= SG; W = convW2; Wr = Wr2; S = SL; }
        Wr[c*256 + t] = W[((t >> 3)*S + c)*8 + (t & 7)];
        return;
    }
    bx -= SG + SL;
    if (t >= 128) return;
    int o = bx, j = t;
    float s = 0.f;
    const float* Wo = fcxrW + o*121*128 + j;
    for (int l = 0; l < 121; ++l) s += Wo[l*128];
    unsafeAtomicAdd(&bias0[j], 0.5f * (cb1[o] + cb2[o]) * s);
}

// ---------------- F1: buildA (fp32 Wr) first, then edge_deg ----------------
__device__ void dev_buildA(const float* __restrict__ Wr, const int* __restrict__ bucket,
                           const int* __restrict__ toff, const int* __restrict__ tcnt,
                           float* __restrict__ A, int S, int V, int bv){
    int b = bv / V, v = bv - b*V;
    int t = threadIdx.x;            // t = o*8+k
    const int* bk = bucket + b*S + toff[b*V + v];
    int m = tcnt[b*V + v];
    float acc = 0.f;
    int idx = 0;
    for (; idx + 4 <= m; idx += 4){
        int c0 = bk[idx], c1 = bk[idx+1], c2 = bk[idx+2], c3 = bk[idx+3];
        acc += Wr[c0*256 + t];
        acc += Wr[c1*256 + t];
        acc += Wr[c2*256 + t];
        acc += Wr[c3*256 + t];
    }
    for (; idx < m; ++idx) acc += Wr[bk[idx]*256 + t];
    A[b*(256*V) + t*V + v] = acc;
}

__global__ void k_F1(const int* __restrict__ dst, const float* __restrict__ ew,
                     double* __restrict__ packed, int* __restrict__ slot,
                     const float* __restrict__ Wr1, const float* __restrict__ Wr2,
                     const int* __restrict__ bucket_g, const int* __restrict__ toff_g,
                     const int* __restrict__ tcnt_g, float* __restrict__ Ag,
                     const int* __restrict__ bucket_l, const int* __restrict__ toff_l,
                     const int* __restrict__ tcnt_l, float* __restrict__ Al){
    int bx = blockIdx.x;
    if (bx < NA){
        if (bx < NB*VG) dev_buildA(Wr1, bucket_g, toff_g, tcnt_g, Ag, SG, VG, bx);
        else dev_buildA(Wr2, bucket_l, toff_l, tcnt_l, Al, SL, VL, bx - NB*VG);
        return;
    }
    int e = (bx - NA)*256 + threadIdx.x;
    double old = unsafeAtomicAdd(&packed[dst[e]], 1048576.0 + (double)ew[e]);
    slot[e] = (int)(old * (1.0/1048576.0));
}

// fused node_dis + gbounds + scan1 (blocks 0..48) + out0 init (block 49)
__global__ void k_prep(const double* __restrict__ packed, int* __restrict__ cnt,
                       float2* __restrict__ dis12, float2* __restrict__ self12,
                       const int* __restrict__ batch, int* __restrict__ gstart,
                       int* __restrict__ bsum,
                       const float* __restrict__ fcxrb, const float* __restrict__ bias0,
                       float* __restrict__ out0){
    __shared__ int sd[256];
    int t = threadIdx.x;
    if (blockIdx.x == 49){
        for (int idx = t; idx < NB*128; idx += 256)
            out0[idx] = fcxrb[idx & 127] + bias0[idx & 127];
        return;
    }
    int base = blockIdx.x*1024;
    int s = 0;
    #pragma unroll
    for (int j = 0; j < 4; ++j){
        int i = base + t*4 + j;
        if (i < NN){
            double p = packed[i];
            int c = (int)(p * (1.0/1048576.0));
            float w = (float)(p - (double)c * 1048576.0);
            cnt[i] = c; s += c;
            float r1 = rsqrtf(w + 1.0f);
            float r2 = rsqrtf((float)c + 1.0f);
            dis12[i] = make_float2(r1, r2);
            self12[i] = make_float2(r1*r1, r2*r2);
            int pb = batch[i];
            int prev = (i == 0) ? -1 : batch[i-1];
            for (int g = prev + 1; g <= pb; ++g) gstart[g] = i;
            if (i == NN - 1){
                for (int g = pb + 1; g <= NG; ++g) gstart[g] = NN;
            }
        }
    }
    sd[t] = s; __syncthreads();
    for (int d = 128; d > 0; d >>= 1){
        if (t < d) sd[t] += sd[t+d];
        __syncthreads();
    }
    if (t == 0) bsum[blockIdx.x] = sd[0];
}

// scan3 with inline cross-block prefix (bsum holds raw per-block sums)
__global__ void k_scan3(const int* __restrict__ cnt, const int* __restrict__ bsum,
                        int* __restrict__ offs){
    __shared__ int sd[256];
    __shared__ int sbase;
    int t = threadIdx.x;
    if (t == 0){
        int run = 0;
        for (int i = 0; i < blockIdx.x; ++i) run += bsum[i];
        sbase = run;
    }
    int base = blockIdx.x*1024;
    int loc[4]; int s = 0;
    #pragma unroll
    for (int j = 0; j < 4; ++j){
        int idx = base + t*4 + j;
        loc[j] = (idx < NN) ? cnt[idx] : 0;
        s += loc[j];
    }
    sd[t] = s; __syncthreads();
    for (int d = 1; d < 256; d <<= 1){
        int v = (t >= d) ? sd[t-d] : 0;
        __syncthreads();
        sd[t] += v;
        __syncthreads();
    }
    int run = sbase + (sd[t] - s);
    #pragma unroll
    for (int j = 0; j < 4; ++j){
        int idx = base + t*4 + j;
        if (idx < NN) offs[idx] = run;
        run += loc[j];
    }
}

// ---------------- F2: buildG FIRST, then scatter, then cast ----------------
__device__ void dev_buildG(float (*rows)[128], const float* __restrict__ emb,
                           const float* __restrict__ W, bf16* __restrict__ G,
                           int V, int q){
    int o = q / V, mt = q - o*V;      // M = 8V, one block = 8 consecutive m
    int t = threadIdx.x;              // 256
    int j = t & 127, half = t >> 7;
    int kk[4];
    #pragma unroll
    for (int qq = 0; qq < 4; ++qq){
        int mm = half*4 + qq;
        int m = mt*8 + mm;
        int k = m / V, v = m - k*V;
        kk[qq] = k;
        rows[mm][j] = emb[v*128 + j];
    }
    __syncthreads();
    float a0=0.f, a1=0.f, a2=0.f, a3=0.f;
    const float* Wo = W + o*121*128 + j;
    for (int l = 0; l < 121; ++l){
        float w = Wo[l*128];
        a0 += rows[half*4+0][l + kk[0]] * w;
        a1 += rows[half*4+1][l + kk[1]] * w;
        a2 += rows[half*4+2][l + kk[2]] * w;
        a3 += rows[half*4+3][l + kk[3]] * w;
    }
    int M = 8*V;
    int base = (o*M + mt*8 + half*4)*128 + j;
    G[base      ] = __float2bfloat16(a0);
    G[base + 128] = __float2bfloat16(a1);
    G[base + 256] = __float2bfloat16(a2);
    G[base + 384] = __float2bfloat16(a3);
}

// blocks [0,NGB): buildG; [NGB, NGB+EDB): scatter; rest: cast.
// epk record: (srcByteOff stride40, n1, n2, srcByteOff stride72)
__global__ void k_F2(const int* __restrict__ src, const int* __restrict__ dst,
                     const float* __restrict__ ew, const float2* __restrict__ dis12,
                     const int* __restrict__ offs, const int* __restrict__ slot,
                     float4* __restrict__ epk,
                     const float* __restrict__ emb1, const float* __restrict__ emb2,
                     const float* __restrict__ fcxrW, bf16* __restrict__ G1,
                     bf16* __restrict__ G2,
                     const float* __restrict__ pro_x, bf16* __restrict__ xb0){
    __shared__ float rows[8][128];
    int bx = blockIdx.x;
    if (bx < 32*VG){ dev_buildG(rows, emb1, fcxrW, G1, VG, bx); return; }
    if (bx < NGB){ dev_buildG(rows, emb2, fcxrW, G2, VL, bx - 32*VG); return; }
    bx -= NGB;
    if (bx < EDB){
        int e = bx*256 + threadIdx.x;
        int s = src[e], d = dst[e];
        int pos = offs[d] + slot[e];
        float2 a = dis12[s], b = dis12[d];
        float4 v;
        v.x = __int_as_float(s*80);    // byte offset, stride-40 bf16
        v.y = a.x * ew[e] * b.x;       // norm layer 1
        v.z = a.y * b.y;               // norm layers 2/3
        v.w = __int_as_float(s*144);   // byte offset, stride-72 bf16
        epk[pos] = v;
        return;
    }
    bx -= EDB;
    int i = bx*256 + threadIdx.x;     // cast pro_x -> padded bf16 [NN,40]
    if (i >= NN*40) return;
    int n = i / 40, f = i - n*40;
    xb0[i] = __float2bfloat16(f < 33 ? pro_x[n*33 + f] : 0.f);
}

// ---------------- fused aggregate + GEMM (uint4 rows) ----------------
template<int QV, int GRP, int OFF_W, int N_Z>
__device__ void dev_agg(float* sAgg /* [4][QV*8] */,
                        const bf16* __restrict__ xb, const float4* __restrict__ epk,
                        const int* __restrict__ offs, const int* __restrict__ cnt,
                        const float2* __restrict__ self12,
                        const float* __restrict__ W, const float* __restrict__ bias,
                        float* __restrict__ tout, int F, int OF, int bx){
    const int LPG = 64 / GRP;
    int wave = threadIdx.x >> 6;
    int node = bx*4 + wave;
    int lane = threadIdx.x & 63;
    int grp  = lane / LPG;
    int gl   = lane % LPG;
    bool act = gl < QV;
    const char* xc = (const char*)xb;
    float a0=0,a1=0,a2=0,a3=0,a4=0,a5=0,a6=0,a7=0;
    int b = offs[node], e = b + cnt[node];
    if (act){
        int fo = gl << 4;   // lane byte offset within row
        if (grp == 0){
            float2 sw2 = self12[node];
            float sw = N_Z ? sw2.y : sw2.x;
            uint4 u = *(const uint4*)(xc + node*(QV*16) + fo);
            a0 = sw*blo(u.x); a1 = sw*bhi(u.x); a2 = sw*blo(u.y); a3 = sw*bhi(u.y);
            a4 = sw*blo(u.z); a5 = sw*bhi(u.z); a6 = sw*blo(u.w); a7 = sw*bhi(u.w);
        }
        int p = b + grp;
        for (; p + 3*GRP < e; p += 4*GRP){
            float4 e0 = epk[p];
            float4 e1 = epk[p +   GRP];
            float4 e2 = epk[p + 2*GRP];
            float4 e3 = epk[p + 3*GRP];
            int o0 = __float_as_int(OFF_W ? e0.w : e0.x); float n0 = N_Z ? e0.z : e0.y;
            int o1 = __float_as_int(OFF_W ? e1.w : e1.x); float n1 = N_Z ? e1.z : e1.y;
            int o2 = __float_as_int(OFF_W ? e2.w : e2.x); float n2 = N_Z ? e2.z : e2.y;
            int o3 = __float_as_int(OFF_W ? e3.w : e3.x); float n3 = N_Z ? e3.z : e3.y;
            uint4 u0 = *(const uint4*)(xc + o0 + fo);
            uint4 u1 = *(const uint4*)(xc + o1 + fo);
            uint4 u2 = *(const uint4*)(xc + o2 + fo);
            uint4 u3 = *(const uint4*)(xc + o3 + fo);
            a0 += n0*blo(u0.x); a1 += n0*bhi(u0.x); a2 += n0*blo(u0.y); a3 += n0*bhi(u0.y);
            a4 += n0*blo(u0.z); a5 += n0*bhi(u0.z); a6 += n0*blo(u0.w); a7 += n0*bhi(u0.w);
            a0 += n1*blo(u1.x); a1 += n1*bhi(u1.x); a2 += n1*blo(u1.y); a3 += n1*bhi(u1.y);
            a4 += n1*blo(u1.z); a5 += n1*bhi(u1.z); a6 += n1*blo(u1.w); a7 += n1*bhi(u1.w);
            a0 += n2*blo(u2.x); a1 += n2*bhi(u2.x); a2 += n2*blo(u2.y); a3 += n2*bhi(u2.y);
            a4 += n2*blo(u2.z); a5 += n2*bhi(u2.z); a6 += n2*blo(u2.w); a7 += n2*bhi(u2.w);
            a0 += n3*blo(u3.x); a1 += n3*bhi(u3.x); a2 += n3*blo(u3.y); a3 += n3*bhi(u3.y);
            a4 += n3*blo(u3.z); a5 += n3*bhi(u3.z); a6 += n3*blo(u3.w); a7 += n3*bhi(u3.w);
        }
        for (; p < e; p += GRP){
            float4 e0 = epk[p];
            int o0 = __float_as_int(OFF_W ? e0.w : e0.x); float n0 = N_Z ? e0.z : e0.y;
            uint4 u0 = *(const uint4*)(xc + o0 + fo);
            a0 += n0*blo(u0.x); a1 += n0*bhi(u0.x); a2 += n0*blo(u0.y); a3 += n0*bhi(u0.y);
            a4 += n0*blo(u0.z); a5 += n0*bhi(u0.z); a6 += n0*blo(u0.w); a7 += n0*bhi(u0.w);
        }
    }
    #pragma unroll
    for (int m = LPG; m < 64; m <<= 1){
        a0 += __shfl_xor(a0, m); a1 += __shfl_xor(a1, m);
        a2 += __shfl_xor(a2, m); a3 += __shfl_xor(a3, m);
        a4 += __shfl_xor(a4, m); a5 += __shfl_xor(a5, m);
        a6 += __shfl_xor(a6, m); a7 += __shfl_xor(a7, m);
    }
    if (act && grp == 0){
        float4* dst = (float4*)&sAgg[wave*(QV*8) + gl*8];
        dst[0] = make_float4(a0, a1, a2, a3);
        dst[1] = make_float4(a4, a5, a6, a7);
    }
    __syncthreads();
    int i0 = bx*4;
    int j = threadIdx.x;
    if (j < OF){
        float c0 = bias[j], c1 = c0, c2 = c0, c3 = c0;
        const float* Wj = W + j;
        const float* s0 = sAgg;
        const float* s1 = sAgg + QV*8;
        const float* s2 = sAgg + 2*QV*8;
        const float* s3 = sAgg + 3*QV*8;
        #pragma unroll 4
        for (int f = 0; f < F; ++f){
            float w = Wj[f*OF];
            c0 += s0[f]*w; c1 += s1[f]*w; c2 += s2[f]*w; c3 += s3[f]*w;
        }
        tout[(size_t)(i0+0)*OF + j] = c0;
        tout[(size_t)(i0+1)*OF + j] = c1;
        tout[(size_t)(i0+2)*OF + j] = c2;
        tout[(size_t)(i0+3)*OF + j] = c3;
    }
}

template<int QV, int GRP, int OFF_W, int N_Z>
__global__ void k_agg_gemm(const bf16* __restrict__ xb, const float4* __restrict__ epk,
                           const int* __restrict__ offs, const int* __restrict__ cnt,
                           const float2* __restrict__ self12,
                           const float* __restrict__ W, const float* __restrict__ bias,
                           float* __restrict__ tout, int F, int OF){
    __shared__ float sAgg[4*QV*8];
    dev_agg<QV,GRP,OFF_W,N_Z>(sAgg, xb, epk, offs, cnt, self12, W, bias,
                              tout, F, OF, blockIdx.x);
}

// gemmR for 256 threads: 8 b-rows x 256-K slice, atomic epilogue
__device__ void dev_gemmR(float* xs /* [8][256] */, int bq,
                          const float* __restrict__ Ag, const bf16* __restrict__ G1,
                          const float* __restrict__ Al, const bf16* __restrict__ G2,
                          float* __restrict__ out0){
    int kpart = bq >> 4;       // 0..69
    int bgrp  = bq & 15;
    const float* X; const bf16* G; int K, k0;
    if (kpart < 5){ X = Ag; G = G1; K = 1280;  k0 = kpart*256; }
    else          { X = Al; G = G2; K = 16640; k0 = (kpart-5)*256; }
    int b0 = bgrp*8;
    int t = threadIdx.x;
    #pragma unroll
    for (int i = 0; i < 8; ++i)
        xs[i*256 + t] = X[(b0+i)*K + k0 + t];
    __syncthreads();
    int rq = t >> 7, j = t & 127;
    const float* x0 = xs + (rq*4)*256;
    float a0=0,a1=0,a2=0,a3=0;
    const bf16* Gp = G + (size_t)k0*128 + j;
    for (int kk = 0; kk < 256; ++kk){
        float g = b2f(Gp[kk*128]);
        a0 += x0[kk]*g; a1 += x0[256+kk]*g; a2 += x0[512+kk]*g; a3 += x0[768+kk]*g;
    }
    unsafeAtomicAdd(&out0[(b0+rq*4+0)*128 + j], 0.5f*a0);
    unsafeAtomicAdd(&out0[(b0+rq*4+1)*128 + j], 0.5f*a1);
    unsafeAtomicAdd(&out0[(b0+rq*4+2)*128 + j], 0.5f*a2);
    unsafeAtomicAdd(&out0[(b0+rq*4+3)*128 + j], 0.5f*a3);
}

// L3 aggregate+gemm  U  gemmR (RNA head backfills L3's latency stalls)
__global__ void k_L3(const bf16* __restrict__ xb, const float4* __restrict__ epk,
                     const int* __restrict__ offs, const int* __restrict__ cnt,
                     const float2* __restrict__ self12,
                     const float* __restrict__ W, const float* __restrict__ bias,
                     float* __restrict__ tout,
                     const float* __restrict__ Ag, const bf16* __restrict__ G1,
                     const float* __restrict__ Al, const bf16* __restrict__ G2,
                     float* __restrict__ out0){
    __shared__ float smem[8*256];
    int bx = blockIdx.x;
    if (bx < AGB){
        dev_agg<9,4,1,1>(smem, xb, epk, offs, cnt, self12, W, bias, tout, 66, 132, bx);
    } else {
        dev_gemmR(smem, bx - AGB, Ag, G1, Al, G2, out0);
    }
}

__global__ void k_bn_stats(const float* __restrict__ t, float* __restrict__ sums, int OF){
    int f = threadIdx.x;
    if (f >= OF) return;
    float s = 0.f, ss = 0.f;
    for (int i = blockIdx.x; i < NN; i += gridDim.x){
        float v = t[(size_t)i*OF + f];
        s += v; ss += v*v;
    }
    unsafeAtomicAdd(&sums[f], s);
    unsafeAtomicAdd(&sums[OF + f], ss);
}

// fused finalize+apply, flattened; padded bf16 out (stride OS)
__global__ void k_bn_apply(const float* __restrict__ t, const float* __restrict__ sums,
                           const float* __restrict__ g, const float* __restrict__ b,
                           bf16* __restrict__ xo, int OF, int OS, int total){
    int id = blockIdx.x*256 + threadIdx.x;
    if (id >= total) return;
    int i = id / OS, f = id - i*OS;
    float v = 0.f;
    if (f < OF){
        float m  = sums[f] * (1.0f/(float)NN);
        float vr = sums[OF + f] * (1.0f/(float)NN) - m*m;
        float sc = g[f] * rsqrtf(vr + 1e-5f);
        float sh = b[f] - m*sc;
        v = t[(size_t)i*OF + f] * sc + sh;
        v = v > 0.f ? v : 0.f;
    }
    xo[id] = __float2bfloat16(v);
}

// pool with BN3+relu inline, reading fp32 t; grid (NG,4) strips
__global__ void k_poolBN(const float* __restrict__ t, const float* __restrict__ sums,
                         const float* __restrict__ g, const float* __restrict__ b,
                         const int* __restrict__ gstart, float* __restrict__ poolsum){
    int gr = blockIdx.x, strip = blockIdx.y, f = threadIdx.x;
    if (f >= 132) return;
    float m  = sums[f] * (1.0f/(float)NN);
    float vr = sums[132 + f] * (1.0f/(float)NN) - m*m;
    float sc = g[f] * rsqrtf(vr + 1e-5f);
    float sh = b[f] - m*sc;
    int i0 = gstart[gr], i1 = gstart[gr+1];
    float s = 0.f;
    for (int i = i0 + strip; i < i1; i += 4){
        float v = t[(size_t)i*132 + f] * sc + sh;
        s += v > 0.f ? v : 0.f;
    }
    unsafeAtomicAdd(&poolsum[gr*132 + f], s);
}

// fused fcg1+fcg2: block g computes h[g,:] in LDS then the 128-out GEMV
__global__ void k_fcgF(const float* __restrict__ poolsum, const int* __restrict__ gstart,
                       const float* __restrict__ W1, const float* __restrict__ b1,
                       const float* __restrict__ W2, const float* __restrict__ b2,
                       float* __restrict__ out){
    __shared__ float pr[132];
    __shared__ float hr[1024];
    __shared__ float part[8][128];
    int g = blockIdx.x, t = threadIdx.x;   // 1024
    if (t < 132){
        float inv = 1.0f / fmaxf((float)(gstart[g+1] - gstart[g]), 1.0f);
        pr[t] = poolsum[g*132 + t] * inv;
    }
    __syncthreads();
    float acc = b1[t];
    #pragma unroll 4
    for (int f = 0; f < 132; ++f) acc += pr[f] * W1[f*1024 + t];
    hr[t] = acc > 0.f ? acc : 0.f;
    __syncthreads();
    int ks = t >> 7, j = t & 127;
    const float* Wp = W2 + (ks*128)*128 + j;
    const float* hp = hr + ks*128;
    float a = 0.f;
    #pragma unroll 8
    for (int kk = 0; kk < 128; ++kk) a += hp[kk] * Wp[(size_t)kk*128];
    part[ks][j] = a;
    __syncthreads();
    if (t < 128){
        float s = b2[t];
        #pragma unroll
        for (int r = 0; r < 8; ++r) s += part[r][t];
        out[g*128 + t] = s;
    }
}

extern "C" void kernel_launch(void* const* d_in, const int* in_sizes, int n_in,
                              void* d_out, int out_size, void* d_ws, size_t ws_size,
                              hipStream_t stream)
{
    (void)in_sizes; (void)n_in; (void)out_size; (void)ws_size;

    const float* pro_x  = (const float*)d_in[0];
    const int*   eidx   = (const int*)  d_in[1];
    const float* ew     = (const float*)d_in[2];
    const int*   pbatch = (const int*)  d_in[3];
    const int*   rna_g  = (const int*)  d_in[4];
    const int*   rna_l  = (const int*)  d_in[5];
    const float* emb1   = (const float*)d_in[6];
    const float* emb2   = (const float*)d_in[7];
    const float* convW1 = (const float*)d_in[8];
    const float* convb1 = (const float*)d_in[9];
    const float* convW2 = (const float*)d_in[10];
    const float* convb2 = (const float*)d_in[11];
    const float* fcxrW  = (const float*)d_in[12];
    const float* fcxrb  = (const float*)d_in[13];
    const float* g1W = (const float*)d_in[14];
    const float* g1b = (const float*)d_in[15];
    const float* g2W = (const float*)d_in[16];
    const float* g2b = (const float*)d_in[17];
    const float* g3W = (const float*)d_in[18];
    const float* g3b = (const float*)d_in[19];
    const float* bn1g = (const float*)d_in[20];
    const float* bn1b = (const float*)d_in[21];
    const float* bn2g = (const float*)d_in[22];
    const float* bn2b = (const float*)d_in[23];
    const float* bn3g = (const float*)d_in[24];
    const float* bn3b = (const float*)d_in[25];
    const float* fcg1W = (const float*)d_in[26];
    const float* fcg1b = (const float*)d_in[27];
    const float* fcg2W = (const float*)d_in[28];
    const float* fcg2b = (const float*)d_in[29];

    const int* e_src = eidx;
    const int* e_dst = eidx + NE;

    char* base = (char*)d_ws;
    size_t off = 0;
    auto alloc = [&](size_t bytes)->char*{
        off = (off + 255) & ~(size_t)255;
        char* p = base + off; off += bytes; return p;
    };

    // ---- zero zone (single memset) ----
    double* packed  = (double*)alloc(NN*8);
    float* bnsum1  = (float*)alloc(2*33*4);
    float* bnsum2  = (float*)alloc(2*66*4);
    float* bnsum3  = (float*)alloc(2*132*4);
    float* poolsum = (float*)alloc(NG*132*4);
    float* bias0   = (float*)alloc(128*4);
    size_t zero_bytes = (off + 255) & ~(size_t)255;

    // ---- persistent buffers ----
    int*    cnt    = (int*)   alloc(NN*4);
    float2* dis12  = (float2*)alloc(NN*8);
    float2* self12 = (float2*)alloc(NN*8);
    int*    offs   = (int*)   alloc(NN*4);
    int*    bsum   = (int*)   alloc(64*4);
    int*    gstart = (int*)   alloc((NG+1)*4);
    float4* epk    = (float4*)alloc((size_t)NE*16);
    float*  bufB   = (float*) alloc((size_t)NN*132*4);   // t (max OF=132)
    bf16*   xbA    = (bf16*)  alloc((size_t)NE*4);       // >= max(slot 6.4MB, NN*40*2)
    bf16*   xbB    = (bf16*)  alloc((size_t)NN*72*2);    // stride-72 features
    float*  Ag     = (float*) alloc((size_t)NB*256*VG*4);   // persistent: read by k_L3
    float*  Al     = (float*) alloc((size_t)NB*256*VL*4);
    bf16*   G1     = (bf16*)  alloc((size_t)32*8*VG*128*2);
    bf16*   G2     = (bf16*)  alloc((size_t)32*8*VL*128*2);

    // slot aliases xbA (consumed by F2 scatter before L1 bn_apply writes xbA)
    int*  slot = (int*)xbA;
    // xb0 (stride-40 cast, 4MB) aliases xbB (first written by L2 bn_apply)
    bf16* xb0  = (bf16*)xbB;

    float* out0 = (float*)d_out;          // xc_rna
    float* out1 = (float*)d_out + 16384;  // xp_out

    // ---- RNA scratch aliased onto bufB (consumed by k_front/F1/F2,
    // which complete before L1 agg_gemm writes bufB) ----
    char* rb = (char*)bufB;
    size_t ro = 0;
    auto ralloc = [&](size_t bytes)->char*{
        ro = (ro + 255) & ~(size_t)255;
        char* p = rb + ro; ro += bytes; return p;
    };
    int* toff_g   = (int*)ralloc(NB*VG*4);
    int* toff_l   = (int*)ralloc(NB*VL*4);
    int* tcnt_g   = (int*)ralloc(NB*VG*4);
    int* tcnt_l   = (int*)ralloc(NB*VL*4);
    int* bucket_g = (int*)ralloc((size_t)NB*SG*4);
    int* bucket_l = (int*)ralloc((size_t)NB*SL*4);
    float* Wr1    = (float*)ralloc((size_t)SG*256*4);
    float* Wr2    = (float*)ralloc((size_t)SL*256*4);

    hipMemsetAsync(d_ws, 0, zero_bytes, stream);

    // ---- front: bucketing U transposeW U bias0_acc ----
    k_front<<<2*NB + SG + SL + 32, 256, 0, stream>>>(
        rna_g, rna_l, tcnt_g, toff_g, bucket_g, tcnt_l, toff_l, bucket_l,
        convW1, convW2, Wr1, Wr2, fcxrW, convb1, convb2, bias0);

    // ---- F1: buildA first (fp32 Wr), edge histogram streams after ----
    k_F1<<<NA + EDB, 256, 0, stream>>>(e_dst, ew, packed, slot,
                                       Wr1, Wr2,
                                       bucket_g, toff_g, tcnt_g, Ag,
                                       bucket_l, toff_l, tcnt_l, Al);
    k_prep<<<50, 256, 0, stream>>>(packed, cnt, dis12, self12, pbatch, gstart,
                                   bsum, fcxrb, bias0, out0);
    k_scan3<<<49, 256, 0, stream>>>(cnt, bsum, offs);

    // ---- F2: buildG first, then edge scatter, then cast ----
    k_F2<<<NGB + EDB + CASTB, 256, 0, stream>>>(
        e_src, e_dst, ew, dis12, offs, slot, epk,
        emb1, emb2, fcxrW, G1, G2, pro_x, xb0);

    // ---- GCN layer 1 (33 -> 33), input stride 40 ----
    k_agg_gemm<5,8,0,0><<<AGB, 256, 0, stream>>>(xb0, epk, offs, cnt, self12,
                                                 g1W, g1b, bufB, 33, 33);
    k_bn_stats<<<256, 64, 0, stream>>>(bufB, bnsum1, 33);
    k_bn_apply<<<(NN*40+255)/256, 256, 0, stream>>>(bufB, bnsum1, bn1g, bn1b,
                                                    xbA, 33, 40, NN*40);

    // ---- GCN layer 2 (33 -> 66), output stride 72 ----
    k_agg_gemm<5,8,0,1><<<AGB, 256, 0, stream>>>(xbA, epk, offs, cnt, self12,
                                                 g2W, g2b, bufB, 33, 66);
    k_bn_stats<<<256, 128, 0, stream>>>(bufB, bnsum2, 66);
    k_bn_apply<<<(NN*72+255)/256, 256, 0, stream>>>(bufB, bnsum2, bn2g, bn2b,
                                                    xbB, 66, 72, NN*72);

    // ---- GCN layer 3 (66 -> 132)  U  RNA-head gemmR ----
    k_L3<<<AGB + 1120, 256, 0, stream>>>(xbB, epk, offs, cnt, self12,
                                         g3W, g3b, bufB, Ag, G1, Al, G2, out0);
    k_bn_stats<<<256, 192, 0, stream>>>(bufB, bnsum3, 132);

    // ---- pool (BN3+relu inline) + fused head ----
    k_poolBN<<<dim3(NG,4), 192, 0, stream>>>(bufB, bnsum3, bn3g, bn3b, gstart, poolsum);
    k_fcgF<<<NG, 1024, 0, stream>>>(poolsum, gstart, fcg1W, fcg1b, fcg2W, fcg2b, out1);
}